// Round 1
// baseline (1797.647 us; speedup 1.0000x reference)
//
#include <hip/hip_runtime.h>

// Problem constants (GNNRNNModel_18270790877883)
constexpr int NN = 20000;   // nodes
constexpr int NE = 320000;  // edges
constexpr int TT = 12;      // timesteps
constexpr int CIN = 128;    // in channels
constexpr int GH = 64;      // gnn hidden
constexpr int RH = 128;     // rnn hidden

__device__ __forceinline__ float sigf(float x) { return 1.0f / (1.0f + __expf(-x)); }
__device__ __forceinline__ float tanh_fast(float x) { return 1.0f - 2.0f / (__expf(2.0f * x) + 1.0f); }

// ---------------- graph preprocessing ----------------

__global__ __launch_bounds__(256) void degree_kernel(const int* __restrict__ dst, int* __restrict__ deg) {
    int e = blockIdx.x * blockDim.x + threadIdx.x;
    if (e < NE) atomicAdd(&deg[dst[e]], 1);
}

__global__ __launch_bounds__(256) void dinv_kernel(const int* __restrict__ deg, float* __restrict__ dinv) {
    int n = blockIdx.x * blockDim.x + threadIdx.x;
    if (n < NN) dinv[n] = rsqrtf((float)deg[n] + 1.0f);  // +1 self loop
}

__global__ __launch_bounds__(1024) void scan_kernel(const int* __restrict__ deg, int* __restrict__ row_ptr,
                                                    int* __restrict__ cursor) {
    __shared__ int sums[1024];
    int t = threadIdx.x;
    const int per = (NN + 1023) / 1024;
    int start = t * per;
    int end = min(start + per, NN);
    int s = 0;
    for (int i = start; i < end; ++i) s += deg[i];
    sums[t] = s;
    __syncthreads();
    for (int off = 1; off < 1024; off <<= 1) {
        int v = (t >= off) ? sums[t - off] : 0;
        __syncthreads();
        sums[t] += v;
        __syncthreads();
    }
    int run = (t == 0) ? 0 : sums[t - 1];
    for (int i = start; i < end; ++i) {
        row_ptr[i] = run;
        cursor[i] = run;
        run += deg[i];
    }
    if (t == 1023) row_ptr[NN] = sums[1023];
}

__global__ __launch_bounds__(256) void scatter_kernel(const int* __restrict__ src, const int* __restrict__ dst,
                                                      const float* __restrict__ dinv, int* __restrict__ cursor,
                                                      int* __restrict__ csr_src, float* __restrict__ csr_norm) {
    int e = blockIdx.x * blockDim.x + threadIdx.x;
    if (e >= NE) return;
    int d = dst[e], s = src[e];
    int pos = atomicAdd(&cursor[d], 1);
    csr_src[pos] = s;
    csr_norm[pos] = dinv[s] * dinv[d];
}

// ---------------- weight prep ----------------

__global__ __launch_bounds__(256) void transpose_kernel(const float* __restrict__ W, float* __restrict__ WT,
                                                        int rows, int cols) {
    int i = blockIdx.x * blockDim.x + threadIdx.x;
    if (i >= rows * cols) return;
    int r = i / cols, c = i % cols;
    WT[c * rows + r] = W[i];
}

__global__ __launch_bounds__(256) void bias_kernel(const float* __restrict__ b_ih, const float* __restrict__ b_hh,
                                                   float* __restrict__ bias) {
    int i = blockIdx.x * blockDim.x + threadIdx.x;
    if (i < 4 * RH) bias[i] = b_ih[i] + b_hh[i];
}

// ---------------- GCN: XW GEMM  (M=NN, K=128, N=64) ----------------
// block 256, tile 64x64, K-chunks of 32.  A staged transposed in LDS.

__global__ __launch_bounds__(256) void xw_gemm_kernel(const float* __restrict__ A,  // [NN,128] (x_seq slice)
                                                      const float* __restrict__ B,  // [128,64] gcn_w
                                                      float* __restrict__ C) {      // [NN,64]
    __shared__ float As[32 * 68];
    __shared__ float Bs[32 * 68];
    int m0 = blockIdx.x * 64;
    int tid = threadIdx.x;
    int tm = tid & 15, tn = tid >> 4;
    float acc[4][4] = {};
    for (int kb = 0; kb < CIN; kb += 32) {
        __syncthreads();
#pragma unroll
        for (int l = 0; l < 2; ++l) {   // A: 64 rows x 32 k = 512 float4
            int s = tid + l * 256;
            int row = s >> 3, k4 = s & 7;
            int gm = m0 + row;
            float4 v = make_float4(0.f, 0.f, 0.f, 0.f);
            if (gm < NN) v = *reinterpret_cast<const float4*>(&A[gm * CIN + kb + k4 * 4]);
            As[(k4 * 4 + 0) * 68 + row] = v.x;
            As[(k4 * 4 + 1) * 68 + row] = v.y;
            As[(k4 * 4 + 2) * 68 + row] = v.z;
            As[(k4 * 4 + 3) * 68 + row] = v.w;
        }
#pragma unroll
        for (int l = 0; l < 2; ++l) {   // B: 32 k x 64 cols = 512 float4
            int s = tid + l * 256;
            int kk = s >> 4, c4 = s & 15;
            float4 v = *reinterpret_cast<const float4*>(&B[(kb + kk) * GH + c4 * 4]);
            *reinterpret_cast<float4*>(&Bs[kk * 68 + c4 * 4]) = v;
        }
        __syncthreads();
#pragma unroll
        for (int k = 0; k < 32; ++k) {
            float4 af = *reinterpret_cast<const float4*>(&As[k * 68 + tm * 4]);
            float4 bf = *reinterpret_cast<const float4*>(&Bs[k * 68 + tn * 4]);
            float av[4] = {af.x, af.y, af.z, af.w};
            float bv[4] = {bf.x, bf.y, bf.z, bf.w};
#pragma unroll
            for (int mi = 0; mi < 4; ++mi)
#pragma unroll
                for (int ni = 0; ni < 4; ++ni) acc[mi][ni] += av[mi] * bv[ni];
        }
    }
#pragma unroll
    for (int mi = 0; mi < 4; ++mi) {
        int gm = m0 + tm * 4 + mi;
        if (gm >= NN) continue;
#pragma unroll
        for (int ni = 0; ni < 4; ++ni) C[gm * GH + tn * 4 + ni] = acc[mi][ni];
    }
}

// ---------------- GCN aggregation: one wave per node, lane = channel ----------------

__global__ __launch_bounds__(256) void gather_kernel(const float* __restrict__ xw, const float* __restrict__ dinv,
                                                     const int* __restrict__ row_ptr, const int* __restrict__ csr_src,
                                                     const float* __restrict__ csr_norm, const float* __restrict__ gcn_b,
                                                     float* __restrict__ hs_t) {
    int wid = (blockIdx.x * blockDim.x + threadIdx.x) >> 6;
    int lane = threadIdx.x & 63;
    if (wid >= NN) return;
    float dv = dinv[wid];
    float acc = gcn_b[lane] + dv * dv * xw[wid * GH + lane];
    int e0 = row_ptr[wid], e1 = row_ptr[wid + 1];
    for (int e = e0; e < e1; ++e) {
        int s = csr_src[e];
        float nm = csr_norm[e];
        acc += nm * xw[s * GH + lane];
    }
    hs_t[wid * GH + lane] = acc;
}

// ---------------- LSTM step: fused gates GEMM + elementwise ----------------
// grid = 313*2 blocks; block computes 64 rows x (64 rh-cols x 4 gates).

__global__ __launch_bounds__(256) void lstm_step_kernel(const float* __restrict__ xin,   // [NN,64]
                                                        const float* __restrict__ hin,   // [NN,128]
                                                        const float* __restrict__ wihT,  // [64,512]
                                                        const float* __restrict__ whhT,  // [128,512]
                                                        const float* __restrict__ bias,  // [512]
                                                        float* __restrict__ cio,         // [NN,128] in-place
                                                        float* __restrict__ hout) {      // [NN,128]
    __shared__ float As[32 * 68];
    __shared__ float Bs[32 * 260];
    int bid = blockIdx.x;
    int mb = bid >> 1, cb = bid & 1;
    int m0 = mb * 64, c0 = cb * 64;
    int tid = threadIdx.x;
    int tm = tid & 15, tn = tid >> 4;
    float acc[4][4][4] = {};  // [gate][mi][ni]

#pragma unroll
    for (int ph = 0; ph < 2; ++ph) {
        const float* A = ph ? hin : xin;
        const float* BT = ph ? whhT : wihT;
        int Ka = ph ? RH : GH;
        for (int kb = 0; kb < Ka; kb += 32) {
            __syncthreads();
#pragma unroll
            for (int l = 0; l < 2; ++l) {   // A chunk: 64 rows x 32 k
                int s = tid + l * 256;
                int row = s >> 3, k4 = s & 7;
                int gm = m0 + row;
                float4 v = make_float4(0.f, 0.f, 0.f, 0.f);
                if (gm < NN) v = *reinterpret_cast<const float4*>(&A[gm * Ka + kb + k4 * 4]);
                As[(k4 * 4 + 0) * 68 + row] = v.x;
                As[(k4 * 4 + 1) * 68 + row] = v.y;
                As[(k4 * 4 + 2) * 68 + row] = v.z;
                As[(k4 * 4 + 3) * 68 + row] = v.w;
            }
#pragma unroll
            for (int l = 0; l < 8; ++l) {   // B chunk: 32 k x 256 gate-cols
                int s = tid + l * 256;
                int kk = s >> 6, col4 = s & 63;
                int g = col4 >> 4, cc4 = col4 & 15;
                float4 v = *reinterpret_cast<const float4*>(&BT[(kb + kk) * 512 + g * 128 + c0 + cc4 * 4]);
                *reinterpret_cast<float4*>(&Bs[kk * 260 + g * 64 + cc4 * 4]) = v;
            }
            __syncthreads();
#pragma unroll
            for (int k = 0; k < 32; ++k) {
                float4 af = *reinterpret_cast<const float4*>(&As[k * 68 + tm * 4]);
                float av[4] = {af.x, af.y, af.z, af.w};
#pragma unroll
                for (int g = 0; g < 4; ++g) {
                    float4 bf = *reinterpret_cast<const float4*>(&Bs[k * 260 + g * 64 + tn * 4]);
                    float bv[4] = {bf.x, bf.y, bf.z, bf.w};
#pragma unroll
                    for (int mi = 0; mi < 4; ++mi)
#pragma unroll
                        for (int ni = 0; ni < 4; ++ni) acc[g][mi][ni] += av[mi] * bv[ni];
                }
            }
        }
    }

    // epilogue: gates -> c,h
    float bi[4], bf_[4], bg[4], bo[4];
#pragma unroll
    for (int ni = 0; ni < 4; ++ni) {
        int col = c0 + tn * 4 + ni;
        bi[ni] = bias[col];
        bf_[ni] = bias[128 + col];
        bg[ni] = bias[256 + col];
        bo[ni] = bias[384 + col];
    }
#pragma unroll
    for (int mi = 0; mi < 4; ++mi) {
        int gm = m0 + tm * 4 + mi;
        if (gm >= NN) continue;
#pragma unroll
        for (int ni = 0; ni < 4; ++ni) {
            int col = c0 + tn * 4 + ni;
            float iv = sigf(acc[0][mi][ni] + bi[ni]);
            float fv = sigf(acc[1][mi][ni] + bf_[ni]);
            float gv = tanh_fast(acc[2][mi][ni] + bg[ni]);
            float ov = sigf(acc[3][mi][ni] + bo[ni]);
            float cold = cio[gm * RH + col];
            float cnew = fv * cold + iv * gv;
            cio[gm * RH + col] = cnew;
            hout[gm * RH + col] = ov * tanh_fast(cnew);
        }
    }
}

// ---------------- FC: out[n] = h[n,:] . fc_w + fc_b ----------------

__global__ __launch_bounds__(256) void fc_kernel(const float* __restrict__ h, const float* __restrict__ fc_w,
                                                 const float* __restrict__ fc_b, float* __restrict__ out) {
    int wid = (blockIdx.x * blockDim.x + threadIdx.x) >> 6;
    int lane = threadIdx.x & 63;
    if (wid >= NN) return;
    float p = h[wid * RH + lane] * fc_w[lane] + h[wid * RH + 64 + lane] * fc_w[64 + lane];
#pragma unroll
    for (int off = 32; off > 0; off >>= 1) p += __shfl_down(p, off);
    if (lane == 0) out[wid] = p + fc_b[0];
}

// ---------------- host ----------------

extern "C" void kernel_launch(void* const* d_in, const int* in_sizes, int n_in,
                              void* d_out, int out_size, void* d_ws, size_t ws_size,
                              hipStream_t stream) {
    const float* x_seq = (const float*)d_in[0];
    const int* edge = (const int*)d_in[1];
    const float* gcn_w = (const float*)d_in[2];
    const float* gcn_b = (const float*)d_in[3];
    const float* w_ih = (const float*)d_in[4];
    const float* w_hh = (const float*)d_in[5];
    const float* b_ih = (const float*)d_in[6];
    const float* b_hh = (const float*)d_in[7];
    const float* fc_w = (const float*)d_in[8];
    const float* fc_b = (const float*)d_in[9];
    float* out = (float*)d_out;

    char* w = (char*)d_ws;
    auto carve = [&](size_t bytes) {
        void* p = (void*)w;
        w += (bytes + 255) & ~(size_t)255;
        return p;
    };
    float* dinv = (float*)carve(NN * 4);
    int* deg = (int*)carve(NN * 4);
    int* row_ptr = (int*)carve((NN + 1) * 4);
    int* cursor = (int*)carve(NN * 4);
    int* csr_src = (int*)carve(NE * 4);
    float* csr_norm = (float*)carve(NE * 4);
    float* xw = (float*)carve((size_t)NN * GH * 4);
    float* hs_t = (float*)carve((size_t)NN * GH * 4);
    float* hbuf0 = (float*)carve((size_t)NN * RH * 4);
    float* hbuf1 = (float*)carve((size_t)NN * RH * 4);
    float* cbuf = (float*)carve((size_t)NN * RH * 4);
    float* wihT = (float*)carve((size_t)GH * 512 * 4);
    float* whhT = (float*)carve((size_t)RH * 512 * 4);
    float* bias = (float*)carve(512 * 4);

    hipMemsetAsync(deg, 0, NN * 4, stream);
    hipMemsetAsync(hbuf0, 0, (size_t)NN * RH * 4, stream);
    hipMemsetAsync(cbuf, 0, (size_t)NN * RH * 4, stream);

    const int* e_src = edge;
    const int* e_dst = edge + NE;

    degree_kernel<<<(NE + 255) / 256, 256, 0, stream>>>(e_dst, deg);
    dinv_kernel<<<(NN + 255) / 256, 256, 0, stream>>>(deg, dinv);
    scan_kernel<<<1, 1024, 0, stream>>>(deg, row_ptr, cursor);
    scatter_kernel<<<(NE + 255) / 256, 256, 0, stream>>>(e_src, e_dst, dinv, cursor, csr_src, csr_norm);

    transpose_kernel<<<(512 * GH + 255) / 256, 256, 0, stream>>>(w_ih, wihT, 512, GH);
    transpose_kernel<<<(512 * RH + 255) / 256, 256, 0, stream>>>(w_hh, whhT, 512, RH);
    bias_kernel<<<2, 256, 0, stream>>>(b_ih, b_hh, bias);

    float* hprev = hbuf0;
    float* hnext = hbuf1;
    const int mblocks = (NN + 63) / 64;  // 313
    for (int t = 0; t < TT; ++t) {
        xw_gemm_kernel<<<mblocks, 256, 0, stream>>>(x_seq + (size_t)t * NN * CIN, gcn_w, xw);
        gather_kernel<<<(NN + 3) / 4, 256, 0, stream>>>(xw, dinv, row_ptr, csr_src, csr_norm, gcn_b, hs_t);
        lstm_step_kernel<<<mblocks * 2, 256, 0, stream>>>(hs_t, hprev, wihT, whhT, bias, cbuf, hnext);
        float* tmp = hprev; hprev = hnext; hnext = tmp;
    }
    fc_kernel<<<(NN + 3) / 4, 256, 0, stream>>>(hprev, fc_w, fc_b, out);
}

// Round 2
// 768.986 us; speedup vs baseline: 2.3377x; 2.3377x over previous
//
#include <hip/hip_runtime.h>

// Problem constants (GNNRNNModel_18270790877883)
constexpr int NN = 20000;   // nodes
constexpr int NE = 320000;  // edges
constexpr int TT = 12;      // timesteps
constexpr int CIN = 128;    // in channels
constexpr int GH = 64;      // gnn hidden
constexpr int RH = 128;     // rnn hidden

typedef __attribute__((ext_vector_type(8))) short short8;
typedef __attribute__((ext_vector_type(4))) float f32x4;

__device__ __forceinline__ float sigf(float x) { return 1.0f / (1.0f + __expf(-x)); }
__device__ __forceinline__ float tanh_fast(float x) { return 1.0f - 2.0f / (__expf(2.0f * x) + 1.0f); }

__device__ __forceinline__ unsigned short f2b_rn(float x) {
    union { float f; unsigned int u; } v; v.f = x;
    unsigned int r = v.u + 0x7FFFu + ((v.u >> 16) & 1u);
    return (unsigned short)(r >> 16);
}

__device__ __forceinline__ void gload_lds16(const void* g, void* l) {
    __builtin_amdgcn_global_load_lds((const __attribute__((address_space(1))) void*)g,
                                     (__attribute__((address_space(3))) void*)l, 16, 0, 0);
}

// ---------------- graph preprocessing ----------------

__global__ __launch_bounds__(256) void degree_kernel(const int* __restrict__ dst, int* __restrict__ deg) {
    int e = blockIdx.x * blockDim.x + threadIdx.x;
    if (e < NE) atomicAdd(&deg[dst[e]], 1);
}

__global__ __launch_bounds__(256) void dinv_kernel(const int* __restrict__ deg, float* __restrict__ dinv) {
    int n = blockIdx.x * blockDim.x + threadIdx.x;
    if (n < NN) dinv[n] = rsqrtf((float)deg[n] + 1.0f);  // +1 self loop
}

__global__ __launch_bounds__(1024) void scan_kernel(const int* __restrict__ deg, int* __restrict__ row_ptr,
                                                    int* __restrict__ cursor) {
    __shared__ int sums[1024];
    int t = threadIdx.x;
    const int per = (NN + 1023) / 1024;
    int start = t * per;
    int end = min(start + per, NN);
    int s = 0;
    for (int i = start; i < end; ++i) s += deg[i];
    sums[t] = s;
    __syncthreads();
    for (int off = 1; off < 1024; off <<= 1) {
        int v = (t >= off) ? sums[t - off] : 0;
        __syncthreads();
        sums[t] += v;
        __syncthreads();
    }
    int run = (t == 0) ? 0 : sums[t - 1];
    for (int i = start; i < end; ++i) {
        row_ptr[i] = run;
        cursor[i] = run;
        run += deg[i];
    }
    if (t == 1023) row_ptr[NN] = sums[1023];
}

__global__ __launch_bounds__(256) void scatter_kernel(const int* __restrict__ src, const int* __restrict__ dst,
                                                      const float* __restrict__ dinv, int* __restrict__ cursor,
                                                      int* __restrict__ csr_src, float* __restrict__ csr_norm) {
    int e = blockIdx.x * blockDim.x + threadIdx.x;
    if (e >= NE) return;
    int d = dst[e], s = src[e];
    int pos = atomicAdd(&cursor[d], 1);
    csr_src[pos] = s;
    csr_norm[pos] = dinv[s] * dinv[d];
}

// ---------------- weight prep (bf16, LDS-image layout, XOR-swizzled granules) ----------------
// LSTM weights: wp[(chunk*512 + col)*4 + gs] (granule of 8 bf16) =
//   WT[col][k], k = chunk*32 + (gs ^ ((col>>1)&3))*8 + j
//   WT[col][k] = k<64 ? w_ih[col][k] : w_hh[col][k-64]   (K = 64(x) + 128(h) = 192, 6 chunks)

__global__ __launch_bounds__(256) void wprep_lstm_kernel(const float* __restrict__ w_ih, const float* __restrict__ w_hh,
                                                         unsigned short* __restrict__ wp) {
    int gidx = blockIdx.x * blockDim.x + threadIdx.x;  // granule id
    if (gidx >= 6 * 512 * 4) return;
    int gs = gidx & 3;
    int col = (gidx >> 2) & 511;
    int chunk = gidx >> 11;
    int g = gs ^ ((col >> 1) & 3);
    int k0 = chunk * 32 + g * 8;
    short8 v;
#pragma unroll
    for (int j = 0; j < 8; ++j) {
        int k = k0 + j;
        float f = (k < 64) ? w_ih[col * 64 + k] : w_hh[col * 128 + (k - 64)];
        v[j] = (short)f2b_rn(f);
    }
    *reinterpret_cast<short8*>(wp + (size_t)gidx * 8) = v;
}

// GCN weight: wx[(chunk*64 + col)*4 + gs] = gcn_w[k][col], k = chunk*32 + (gs ^ ((col>>1)&3))*8 + j
__global__ __launch_bounds__(256) void wprep_gcn_kernel(const float* __restrict__ gcn_w, unsigned short* __restrict__ wx) {
    int gidx = blockIdx.x * blockDim.x + threadIdx.x;
    if (gidx >= 4 * 64 * 4) return;
    int gs = gidx & 3;
    int col = (gidx >> 2) & 63;
    int chunk = gidx >> 8;
    int g = gs ^ ((col >> 1) & 3);
    int k0 = chunk * 32 + g * 8;
    short8 v;
#pragma unroll
    for (int j = 0; j < 8; ++j) v[j] = (short)f2b_rn(gcn_w[(k0 + j) * 64 + col]);
    *reinterpret_cast<short8*>(wx + (size_t)gidx * 8) = v;
}

__global__ __launch_bounds__(256) void bias_kernel(const float* __restrict__ b_ih, const float* __restrict__ b_hh,
                                                   float* __restrict__ bias) {
    int i = blockIdx.x * blockDim.x + threadIdx.x;
    if (i < 4 * RH) bias[i] = b_ih[i] + b_hh[i];
}

// ---------------- GCN XW: bf16 MFMA GEMM  M=NN K=128 N=64 ----------------
// block 256 = 4 waves; tile 64 rows; wave w owns rows [w*16, w*16+16) x all 64 cols.
// A (x fp32) reg-staged with RN convert + swizzled ds_write; B staged via global_load_lds.

__global__ __launch_bounds__(256) void xw_mfma_kernel(const float* __restrict__ x,         // [NN,128] slice
                                                      const unsigned short* __restrict__ wx, // prepped
                                                      float* __restrict__ xw) {            // [NN,64] fp32
    __shared__ __align__(16) char As[4 * 4096];  // [chunk][64 rows][4 gs][16B]
    __shared__ __align__(16) char Bs[4 * 4096];  // [chunk][64 cols][4 gs][16B]
    int tid = threadIdx.x;
    int lane = tid & 63, w = tid >> 6;
    int m0 = blockIdx.x * 64;

    // stage B: 16 KB linear (pre-swizzled in global), 4 issues per wave
#pragma unroll
    for (int j = 0; j < 4; ++j) {
        const unsigned short* src = wx + (size_t)(w * 4 + j) * 512 + lane * 8;
        gload_lds16(src, Bs + (w * 4 + j) * 1024);
    }
    // stage A: thread -> (row = tid>>2, gs = tid&3), all 4 chunks; fp32 -> bf16 RN
    {
        int row = tid >> 2, gs = tid & 3;
        int srow = min(m0 + row, NN - 1);
        int g = gs ^ ((row >> 1) & 3);
        const float* sp = x + (size_t)srow * CIN + g * 8;
#pragma unroll
        for (int c = 0; c < 4; ++c) {
            float4 f0 = *reinterpret_cast<const float4*>(sp + c * 32);
            float4 f1 = *reinterpret_cast<const float4*>(sp + c * 32 + 4);
            short8 v;
            v[0] = (short)f2b_rn(f0.x); v[1] = (short)f2b_rn(f0.y);
            v[2] = (short)f2b_rn(f0.z); v[3] = (short)f2b_rn(f0.w);
            v[4] = (short)f2b_rn(f1.x); v[5] = (short)f2b_rn(f1.y);
            v[6] = (short)f2b_rn(f1.z); v[7] = (short)f2b_rn(f1.w);
            *reinterpret_cast<short8*>(As + c * 4096 + row * 64 + gs * 16) = v;
        }
    }
    __syncthreads();

    f32x4 acc[4] = {};
    int rl = w * 16 + (lane & 15);
    int o = lane >> 4;
#pragma unroll
    for (int c = 0; c < 4; ++c) {
        int gsa = o ^ ((rl >> 1) & 3);
        short8 a = *reinterpret_cast<const short8*>(As + c * 4096 + rl * 64 + gsa * 16);
#pragma unroll
        for (int cn = 0; cn < 4; ++cn) {
            int col = cn * 16 + (lane & 15);
            int gsb = o ^ ((col >> 1) & 3);
            short8 b = *reinterpret_cast<const short8*>(Bs + c * 4096 + col * 64 + gsb * 16);
            acc[cn] = __builtin_amdgcn_mfma_f32_16x16x32_bf16(a, b, acc[cn], 0, 0, 0);
        }
    }
#pragma unroll
    for (int cn = 0; cn < 4; ++cn)
#pragma unroll
        for (int r = 0; r < 4; ++r) {
            int row = m0 + w * 16 + (lane >> 4) * 4 + r;
            int col = cn * 16 + (lane & 15);
            if (row < NN) xw[(size_t)row * GH + col] = acc[cn][r];
        }
}

// ---------------- GCN aggregation: wave per node, lane = channel; fp32 acc -> bf16 out ----------------

__global__ __launch_bounds__(256) void gather_kernel(const float* __restrict__ xw, const float* __restrict__ dinv,
                                                     const int* __restrict__ row_ptr, const int* __restrict__ csr_src,
                                                     const float* __restrict__ csr_norm, const float* __restrict__ gcn_b,
                                                     unsigned short* __restrict__ hs_b) {
    int wid = (blockIdx.x * blockDim.x + threadIdx.x) >> 6;
    int lane = threadIdx.x & 63;
    if (wid >= NN) return;
    float dv = dinv[wid];
    float acc = gcn_b[lane] + dv * dv * xw[(size_t)wid * GH + lane];
    int e0 = row_ptr[wid], e1 = row_ptr[wid + 1];
    for (int e = e0; e < e1; ++e) {
        int s = csr_src[e];
        float nm = csr_norm[e];
        acc += nm * xw[(size_t)s * GH + lane];
    }
    hs_b[(size_t)wid * GH + lane] = f2b_rn(acc);
}

// ---------------- LSTM step: bf16 MFMA, M-tile 32, all 512 gate-cols ----------------
// 4 waves; wave w owns rh-cols [w*32, w*32+32) of ALL FOUR gates -> local c/h epilogue.
// A = [hs(64) | h(128)] K=192, 6 chunks of 32, staged once (global_load_lds, swizzled src).
// B chunk (32k x 512 cols = 32 KB) single-buffered per chunk from prepped global.

__global__ __launch_bounds__(256) void lstm_mfma_kernel(const unsigned short* __restrict__ xin, // hs bf16 [NN,64]
                                                        const unsigned short* __restrict__ hin, // h bf16 [NN,128]
                                                        const unsigned short* __restrict__ wp,  // prepped [6][512][4][8]
                                                        const float* __restrict__ bias,         // [512]
                                                        float* __restrict__ cio,                // fp32 [NN,128]
                                                        unsigned short* __restrict__ hout,      // bf16 [NN,128]
                                                        float* __restrict__ hfp) {              // fp32 h (last step) or null
    __shared__ __align__(16) char As[6 * 2048];   // [chunk][32 rows][4 gs][16B]
    __shared__ __align__(16) char Bs[512 * 64];   // [512 cols][4 gs][16B]
    int tid = threadIdx.x;
    int lane = tid & 63, w = tid >> 6;
    int m0 = blockIdx.x * 32;

    // stage A: 12 issues of 1KB, 3 per wave
    {
        int rg_lane = lane >> 2;  // 0..15
        int gs = lane & 3;
#pragma unroll
        for (int j = 0; j < 3; ++j) {
            int issue = w * 3 + j;        // 0..11
            int chunk = issue >> 1;
            int row = (issue & 1) * 16 + rg_lane;
            int g = gs ^ ((row >> 1) & 3);
            const unsigned short* src;
            if (chunk < 2) src = xin + (size_t)(m0 + row) * GH + chunk * 32 + g * 8;
            else           src = hin + (size_t)(m0 + row) * RH + (chunk - 2) * 32 + g * 8;
            gload_lds16(src, As + issue * 1024);
        }
    }

    f32x4 acc[2][8] = {};  // [m-frag][gate*2 + cn]
    int l15 = lane & 15, o = lane >> 4;

    for (int c = 0; c < 6; ++c) {
        __syncthreads();  // protect Bs from overwrite while prior chunk still read
        // stage B chunk c: 32 KB linear (pre-swizzled), 8 issues per wave
#pragma unroll
        for (int j = 0; j < 8; ++j) {
            const unsigned short* src = wp + (size_t)c * 16384 + w * 4096 + j * 512 + lane * 8;
            gload_lds16(src, Bs + w * 8192 + j * 1024);
        }
        __syncthreads();  // drains vmcnt -> staged data visible

        short8 a[2];
#pragma unroll
        for (int mi = 0; mi < 2; ++mi) {
            int row = mi * 16 + l15;
            int gsa = o ^ ((row >> 1) & 3);
            a[mi] = *reinterpret_cast<const short8*>(As + c * 2048 + row * 64 + gsa * 16);
        }
#pragma unroll
        for (int g = 0; g < 4; ++g)
#pragma unroll
            for (int cn = 0; cn < 2; ++cn) {
                int col = g * 128 + w * 32 + cn * 16 + l15;
                int gsb = o ^ ((col >> 1) & 3);
                short8 b = *reinterpret_cast<const short8*>(Bs + col * 64 + gsb * 16);
                int ni = g * 2 + cn;
                acc[0][ni] = __builtin_amdgcn_mfma_f32_16x16x32_bf16(a[0], b, acc[0][ni], 0, 0, 0);
                acc[1][ni] = __builtin_amdgcn_mfma_f32_16x16x32_bf16(a[1], b, acc[1][ni], 0, 0, 0);
            }
    }

    // epilogue: this wave owns rh-cols [w*32, w*32+32) fully (all 4 gates local)
#pragma unroll
    for (int mi = 0; mi < 2; ++mi) {
        int row0 = m0 + mi * 16 + (lane >> 4) * 4;
#pragma unroll
        for (int cn = 0; cn < 2; ++cn) {
            int col = w * 32 + cn * 16 + l15;
            float bi = bias[col], bff = bias[128 + col], bg = bias[256 + col], bo = bias[384 + col];
#pragma unroll
            for (int r = 0; r < 4; ++r) {
                int row = row0 + r;
                float iv = sigf(acc[mi][0 + cn][r] + bi);
                float fv = sigf(acc[mi][2 + cn][r] + bff);
                float gv = tanh_fast(acc[mi][4 + cn][r] + bg);
                float ov = sigf(acc[mi][6 + cn][r] + bo);
                size_t idx = (size_t)row * RH + col;
                float cold = cio[idx];
                float cnew = fv * cold + iv * gv;
                cio[idx] = cnew;
                float hv = ov * tanh_fast(cnew);
                hout[idx] = f2b_rn(hv);
                if (hfp) hfp[idx] = hv;
            }
        }
    }
}

// ---------------- FC: out[n] = h[n,:] . fc_w + fc_b (fp32 h) ----------------

__global__ __launch_bounds__(256) void fc_kernel(const float* __restrict__ h, const float* __restrict__ fc_w,
                                                 const float* __restrict__ fc_b, float* __restrict__ out) {
    int wid = (blockIdx.x * blockDim.x + threadIdx.x) >> 6;
    int lane = threadIdx.x & 63;
    if (wid >= NN) return;
    float p = h[(size_t)wid * RH + lane] * fc_w[lane] + h[(size_t)wid * RH + 64 + lane] * fc_w[64 + lane];
#pragma unroll
    for (int off = 32; off > 0; off >>= 1) p += __shfl_down(p, off);
    if (lane == 0) out[wid] = p + fc_b[0];
}

// ---------------- host ----------------

extern "C" void kernel_launch(void* const* d_in, const int* in_sizes, int n_in,
                              void* d_out, int out_size, void* d_ws, size_t ws_size,
                              hipStream_t stream) {
    const float* x_seq = (const float*)d_in[0];
    const int* edge = (const int*)d_in[1];
    const float* gcn_w = (const float*)d_in[2];
    const float* gcn_b = (const float*)d_in[3];
    const float* w_ih = (const float*)d_in[4];
    const float* w_hh = (const float*)d_in[5];
    const float* b_ih = (const float*)d_in[6];
    const float* b_hh = (const float*)d_in[7];
    const float* fc_w = (const float*)d_in[8];
    const float* fc_b = (const float*)d_in[9];
    float* out = (float*)d_out;

    char* w = (char*)d_ws;
    auto carve = [&](size_t bytes) {
        void* p = (void*)w;
        w += (bytes + 255) & ~(size_t)255;
        return p;
    };
    float* dinv = (float*)carve(NN * 4);
    int* deg = (int*)carve(NN * 4);
    int* row_ptr = (int*)carve((NN + 1) * 4);
    int* cursor = (int*)carve(NN * 4);
    int* csr_src = (int*)carve(NE * 4);
    float* csr_norm = (float*)carve(NE * 4);
    float* xw = (float*)carve((size_t)NN * GH * 4);
    unsigned short* hs_b = (unsigned short*)carve((size_t)NN * GH * 2);
    unsigned short* hb0 = (unsigned short*)carve((size_t)NN * RH * 2);
    unsigned short* hb1 = (unsigned short*)carve((size_t)NN * RH * 2);
    float* cbuf = (float*)carve((size_t)NN * RH * 4);
    float* hfp = (float*)carve((size_t)NN * RH * 4);
    unsigned short* wp = (unsigned short*)carve((size_t)6 * 512 * 4 * 8 * 2);
    unsigned short* wx = (unsigned short*)carve((size_t)4 * 64 * 4 * 8 * 2);
    float* bias = (float*)carve(512 * 4);

    hipMemsetAsync(deg, 0, NN * 4, stream);
    hipMemsetAsync(hb0, 0, (size_t)NN * RH * 2, stream);
    hipMemsetAsync(cbuf, 0, (size_t)NN * RH * 4, stream);

    const int* e_src = edge;
    const int* e_dst = edge + NE;

    degree_kernel<<<(NE + 255) / 256, 256, 0, stream>>>(e_dst, deg);
    dinv_kernel<<<(NN + 255) / 256, 256, 0, stream>>>(deg, dinv);
    scan_kernel<<<1, 1024, 0, stream>>>(deg, row_ptr, cursor);
    scatter_kernel<<<(NE + 255) / 256, 256, 0, stream>>>(e_src, e_dst, dinv, cursor, csr_src, csr_norm);

    wprep_lstm_kernel<<<(6 * 512 * 4 + 255) / 256, 256, 0, stream>>>(w_ih, w_hh, wp);
    wprep_gcn_kernel<<<(4 * 64 * 4 + 255) / 256, 256, 0, stream>>>(gcn_w, wx);
    bias_kernel<<<2, 256, 0, stream>>>(b_ih, b_hh, bias);

    unsigned short* hprev = hb0;
    unsigned short* hnext = hb1;
    for (int t = 0; t < TT; ++t) {
        xw_mfma_kernel<<<(NN + 63) / 64, 256, 0, stream>>>(x_seq + (size_t)t * NN * CIN, wx, xw);
        gather_kernel<<<(NN + 3) / 4, 256, 0, stream>>>(xw, dinv, row_ptr, csr_src, csr_norm, gcn_b, hs_b);
        lstm_mfma_kernel<<<NN / 32, 256, 0, stream>>>(hs_b, hprev, wp, bias, cbuf, hnext,
                                                      (t == TT - 1) ? hfp : nullptr);
        unsigned short* tmp = hprev; hprev = hnext; hnext = tmp;
    }
    fc_kernel<<<(NN + 3) / 4, 256, 0, stream>>>(hfp, fc_w, fc_b, out);
}

// Round 3
// 518.715 us; speedup vs baseline: 3.4656x; 1.4825x over previous
//
#include <hip/hip_runtime.h>

// Problem constants (GNNRNNModel_18270790877883)
constexpr int NN = 20000;   // nodes
constexpr int NE = 320000;  // edges
constexpr int TT = 12;      // timesteps
constexpr int CIN = 128;    // in channels
constexpr int GH = 64;      // gnn hidden
constexpr int RH = 128;     // rnn hidden
constexpr int TOTAL = TT * NN;  // 240000

typedef __attribute__((ext_vector_type(8))) short short8;
typedef __attribute__((ext_vector_type(4))) float f32x4;

__device__ __forceinline__ float sigf(float x) { return 1.0f / (1.0f + __expf(-x)); }
__device__ __forceinline__ float tanh_fast(float x) { return 1.0f - 2.0f / (__expf(2.0f * x) + 1.0f); }

__device__ __forceinline__ unsigned short f2b_rn(float x) {
    union { float f; unsigned int u; } v; v.f = x;
    unsigned int r = v.u + 0x7FFFu + ((v.u >> 16) & 1u);
    return (unsigned short)(r >> 16);
}
__device__ __forceinline__ float b2f(unsigned short b) {
    union { unsigned int u; float f; } v; v.u = ((unsigned int)b) << 16;
    return v.f;
}

__device__ __forceinline__ void gload_lds16(const void* g, void* l) {
    __builtin_amdgcn_global_load_lds((const __attribute__((address_space(1))) void*)g,
                                     (__attribute__((address_space(3))) void*)l, 16, 0, 0);
}

// ---------------- graph preprocessing ----------------

__global__ __launch_bounds__(256) void degree_kernel(const int* __restrict__ dst, int* __restrict__ deg) {
    int e = blockIdx.x * blockDim.x + threadIdx.x;
    if (e < NE) atomicAdd(&deg[dst[e]], 1);
}

__global__ __launch_bounds__(256) void dinv_kernel(const int* __restrict__ deg, float* __restrict__ dinv) {
    int n = blockIdx.x * blockDim.x + threadIdx.x;
    if (n < NN) dinv[n] = rsqrtf((float)deg[n] + 1.0f);  // +1 self loop
}

__global__ __launch_bounds__(1024) void scan_kernel(const int* __restrict__ deg, int* __restrict__ row_ptr,
                                                    int* __restrict__ cursor) {
    __shared__ int sums[1024];
    int t = threadIdx.x;
    const int per = (NN + 1023) / 1024;
    int start = t * per;
    int end = min(start + per, NN);
    int s = 0;
    for (int i = start; i < end; ++i) s += deg[i];
    sums[t] = s;
    __syncthreads();
    for (int off = 1; off < 1024; off <<= 1) {
        int v = (t >= off) ? sums[t - off] : 0;
        __syncthreads();
        sums[t] += v;
        __syncthreads();
    }
    int run = (t == 0) ? 0 : sums[t - 1];
    for (int i = start; i < end; ++i) {
        row_ptr[i] = run;
        cursor[i] = run;
        run += deg[i];
    }
    if (t == 1023) row_ptr[NN] = sums[1023];
}

__global__ __launch_bounds__(256) void scatter_kernel(const int* __restrict__ src, const int* __restrict__ dst,
                                                      const float* __restrict__ dinv, int* __restrict__ cursor,
                                                      int* __restrict__ csr_src, float* __restrict__ csr_norm) {
    int e = blockIdx.x * blockDim.x + threadIdx.x;
    if (e >= NE) return;
    int d = dst[e], s = src[e];
    int pos = atomicAdd(&cursor[d], 1);
    csr_src[pos] = s;
    csr_norm[pos] = dinv[s] * dinv[d];
}

// ---------------- weight prep (bf16, XOR-swizzled granule layout) ----------------
// wp[(chunk*512 + col)*4 + gs] (granule of 8 bf16) holds WT[col][k],
//   k = chunk*32 + (gs ^ ((col>>1)&3))*8 + j ;  WT[col][k] = k<64 ? w_ih[col][k] : w_hh[col][k-64]

__global__ __launch_bounds__(256) void wprep_lstm_kernel(const float* __restrict__ w_ih, const float* __restrict__ w_hh,
                                                         unsigned short* __restrict__ wp) {
    int gidx = blockIdx.x * blockDim.x + threadIdx.x;  // granule id
    if (gidx >= 6 * 512 * 4) return;
    int gs = gidx & 3;
    int col = (gidx >> 2) & 511;
    int chunk = gidx >> 11;
    int g = gs ^ ((col >> 1) & 3);
    int k0 = chunk * 32 + g * 8;
    short8 v;
#pragma unroll
    for (int j = 0; j < 8; ++j) {
        int k = k0 + j;
        float f = (k < 64) ? w_ih[col * 64 + k] : w_hh[col * 128 + (k - 64)];
        v[j] = (short)f2b_rn(f);
    }
    *reinterpret_cast<short8*>(wp + (size_t)gidx * 8) = v;
}

// GCN weight: wx[(chunk*64 + col)*4 + gs] = gcn_w[k][col], k = chunk*32 + (gs ^ ((col>>1)&3))*8 + j
__global__ __launch_bounds__(256) void wprep_gcn_kernel(const float* __restrict__ gcn_w, unsigned short* __restrict__ wx) {
    int gidx = blockIdx.x * blockDim.x + threadIdx.x;
    if (gidx >= 4 * 64 * 4) return;
    int gs = gidx & 3;
    int col = (gidx >> 2) & 63;
    int chunk = gidx >> 8;
    int g = gs ^ ((col >> 1) & 3);
    int k0 = chunk * 32 + g * 8;
    short8 v;
#pragma unroll
    for (int j = 0; j < 8; ++j) v[j] = (short)f2b_rn(gcn_w[(k0 + j) * 64 + col]);
    *reinterpret_cast<short8*>(wx + (size_t)gidx * 8) = v;
}

__global__ __launch_bounds__(256) void bias_kernel(const float* __restrict__ b_ih, const float* __restrict__ b_hh,
                                                   float* __restrict__ bias) {
    int i = blockIdx.x * blockDim.x + threadIdx.x;
    if (i < 4 * RH) bias[i] = b_ih[i] + b_hh[i];
}

// ---------------- batched XW: bf16 MFMA GEMM  M=240000 K=128 N=64, bf16 out ----------------

__global__ __launch_bounds__(256) void xw_mfma_kernel(const float* __restrict__ x,          // [TOTAL,128]
                                                      const unsigned short* __restrict__ wx,
                                                      unsigned short* __restrict__ xwb) {   // [TOTAL,64] bf16
    __shared__ __align__(16) char As[4 * 4096];  // [chunk][64 rows][4 gs][16B]
    __shared__ __align__(16) char Bs[4 * 4096];  // [chunk][64 cols][4 gs][16B]
    int tid = threadIdx.x;
    int lane = tid & 63, w = tid >> 6;
    int m0 = blockIdx.x * 64;

#pragma unroll
    for (int j = 0; j < 4; ++j) {
        const unsigned short* src = wx + (size_t)(w * 4 + j) * 512 + lane * 8;
        gload_lds16(src, Bs + (w * 4 + j) * 1024);
    }
    {
        int row = tid >> 2, gs = tid & 3;
        int srow = m0 + row;
        int g = gs ^ ((row >> 1) & 3);
        const float* sp = x + (size_t)srow * CIN + g * 8;
#pragma unroll
        for (int c = 0; c < 4; ++c) {
            float4 f0 = *reinterpret_cast<const float4*>(sp + c * 32);
            float4 f1 = *reinterpret_cast<const float4*>(sp + c * 32 + 4);
            short8 v;
            v[0] = (short)f2b_rn(f0.x); v[1] = (short)f2b_rn(f0.y);
            v[2] = (short)f2b_rn(f0.z); v[3] = (short)f2b_rn(f0.w);
            v[4] = (short)f2b_rn(f1.x); v[5] = (short)f2b_rn(f1.y);
            v[6] = (short)f2b_rn(f1.z); v[7] = (short)f2b_rn(f1.w);
            *reinterpret_cast<short8*>(As + c * 4096 + row * 64 + gs * 16) = v;
        }
    }
    __syncthreads();

    f32x4 acc[4] = {};
    int rl = w * 16 + (lane & 15);
    int o = lane >> 4;
#pragma unroll
    for (int c = 0; c < 4; ++c) {
        int gsa = o ^ ((rl >> 1) & 3);
        short8 a = *reinterpret_cast<const short8*>(As + c * 4096 + rl * 64 + gsa * 16);
#pragma unroll
        for (int cn = 0; cn < 4; ++cn) {
            int col = cn * 16 + (lane & 15);
            int gsb = o ^ ((col >> 1) & 3);
            short8 b = *reinterpret_cast<const short8*>(Bs + c * 4096 + col * 64 + gsb * 16);
            acc[cn] = __builtin_amdgcn_mfma_f32_16x16x32_bf16(a, b, acc[cn], 0, 0, 0);
        }
    }
#pragma unroll
    for (int cn = 0; cn < 4; ++cn)
#pragma unroll
        for (int r = 0; r < 4; ++r) {
            int row = m0 + w * 16 + (lane >> 4) * 4 + r;
            int col = cn * 16 + (lane & 15);
            xwb[(size_t)row * GH + col] = f2b_rn(acc[cn][r]);
        }
}

// ---------------- batched GCN aggregation: grid (5000, 12); wave per node, lane = channel ----------------

__global__ __launch_bounds__(256) void gather_kernel(const unsigned short* __restrict__ xwb, const float* __restrict__ dinv,
                                                     const int* __restrict__ row_ptr, const int* __restrict__ csr_src,
                                                     const float* __restrict__ csr_norm, const float* __restrict__ gcn_b,
                                                     unsigned short* __restrict__ hs_b) {
    int t = blockIdx.y;
    int wid = (blockIdx.x * blockDim.x + threadIdx.x) >> 6;
    int lane = threadIdx.x & 63;
    if (wid >= NN) return;
    const unsigned short* slice = xwb + (size_t)t * NN * GH;
    float dv = dinv[wid];
    float acc = gcn_b[lane] + dv * dv * b2f(slice[(size_t)wid * GH + lane]);
    int e0 = row_ptr[wid], e1 = row_ptr[wid + 1];
    for (int e = e0; e < e1; ++e) {
        int s = csr_src[e];
        float nm = csr_norm[e];
        acc += nm * b2f(slice[(size_t)s * GH + lane]);
    }
    hs_b[((size_t)t * NN + wid) * GH + lane] = f2b_rn(acc);
}

// ---------------- persistent LSTM: 250 blocks x 512 thr; block owns 80 rows, loops all 12 steps ----------------
// Wave w owns rh-cols [w*16,w*16+16) of all 4 gates. c in regs; h via LDS (bf16, swizzled).
// B-fragments read directly from L2 (pre-swizzled wp -> 1KB coalesced segments). FC fused at t=11.

#define HS_OFF 0            // 2 slots x [2 chunks][80 rows][4 gs][16B] = 2 x 10240
#define HA_OFF 20480        // [4 chunks][80 rows][4 gs][16B] = 20480
#define RED_OFF 40960       // float [8][80] = 2560
#define SMEM_BYTES 43520

__global__ __launch_bounds__(512, 2) void lstm_persist_kernel(const unsigned short* __restrict__ hs_all, // [TT,NN,64]
                                                              const unsigned short* __restrict__ wp,     // [6][512][4][8]
                                                              const float* __restrict__ bias,            // [512]
                                                              const float* __restrict__ fc_w,            // [128]
                                                              const float* __restrict__ fc_b,            // [1]
                                                              float* __restrict__ out) {                 // [NN]
    __shared__ __align__(16) char smem[SMEM_BYTES];
    int tid = threadIdx.x;
    int lane = tid & 63, w = tid >> 6;
    int l15 = lane & 15, o = lane >> 4;
    int base = blockIdx.x * 80;

    int sw = o ^ ((l15 >> 1) & 3);       // shared swizzle for all A reads and B reads
    int colbase = w * 16 + l15;          // this thread's rh-col
    float bi = bias[colbase], bff = bias[128 + colbase], bg = bias[256 + colbase], bo = bias[384 + colbase];
    float fcw = fc_w[colbase];

    // h-write constants: k = 64 + colbase -> chunk, granule, elem
    int h_chunk = w >> 1;                          // 0..3
    int h_g = ((w & 1) << 1) + (l15 >> 3);         // granule within 32-k chunk
    int h_j = l15 & 7;                             // elem within granule

    // prologue: zero h region, stage hs[0] into slot 0
    {
#pragma unroll
        for (int i = 0; i < 10; ++i) ((int*)(smem + HA_OFF))[tid + i * 512] = 0;
#pragma unroll
        for (int j = 0; j < 2; ++j) {
            int gi = j * 512 + tid;
            if (gi < 640) {
                int cc = (gi >= 320) ? 1 : 0;
                int rem = gi - cc * 320;
                int row = rem >> 2, gs = rem & 3;
                int g = gs ^ ((row >> 1) & 3);
                const unsigned short* src = hs_all + ((size_t)(base + row)) * 64 + cc * 32 + g * 8;
                gload_lds16(src, smem + HS_OFF + gi * 16);
            }
        }
    }

    float c_reg[5][4] = {};
    f32x4 acc[5][4];

#pragma unroll 1
    for (int t = 0; t < TT; ++t) {
        __syncthreads();  // drains vmcnt: hs[t] staged + prev h-writes visible

        // prefetch hs[t+1] into other slot
        if (t + 1 < TT) {
            char* dstb = smem + HS_OFF + ((t + 1) & 1) * 10240;
#pragma unroll
            for (int j = 0; j < 2; ++j) {
                int gi = j * 512 + tid;
                if (gi < 640) {
                    int cc = (gi >= 320) ? 1 : 0;
                    int rem = gi - cc * 320;
                    int row = rem >> 2, gs = rem & 3;
                    int g = gs ^ ((row >> 1) & 3);
                    const unsigned short* src = hs_all + ((size_t)(t + 1) * NN + base + row) * 64 + cc * 32 + g * 8;
                    gload_lds16(src, dstb + gi * 16);
                }
            }
        }

#pragma unroll
        for (int mi = 0; mi < 5; ++mi)
#pragma unroll
            for (int g = 0; g < 4; ++g) acc[mi][g] = (f32x4){0.f, 0.f, 0.f, 0.f};

        const char* hsb = smem + HS_OFF + (t & 1) * 10240;
#pragma unroll
        for (int c = 0; c < 6; ++c) {
            // B frags: direct from L2 (1KB coalesced per wave per (c,g))
            short8 b[4];
#pragma unroll
            for (int g = 0; g < 4; ++g) {
                size_t goff = ((size_t)(c * 512 + g * 128 + colbase) * 4 + sw) * 8;
                b[g] = *reinterpret_cast<const short8*>(wp + goff);
            }
            const char* abase = (c < 2) ? (hsb + c * 5120) : (smem + HA_OFF + (c - 2) * 5120);
            short8 a[5];
#pragma unroll
            for (int mi = 0; mi < 5; ++mi)
                a[mi] = *reinterpret_cast<const short8*>(abase + (mi * 16 + l15) * 64 + sw * 16);
#pragma unroll
            for (int g = 0; g < 4; ++g)
#pragma unroll
                for (int mi = 0; mi < 5; ++mi)
                    acc[mi][g] = __builtin_amdgcn_mfma_f32_16x16x32_bf16(a[mi], b[g], acc[mi][g], 0, 0, 0);
        }

        __syncthreads();  // all reads of h region done before overwrite

        // epilogue: thread covers rows mi*16 + o*4 + r, col = colbase
        if (t + 1 < TT) {
#pragma unroll
            for (int mi = 0; mi < 5; ++mi)
#pragma unroll
                for (int r = 0; r < 4; ++r) {
                    float iv = sigf(acc[mi][0][r] + bi);
                    float fv = sigf(acc[mi][1][r] + bff);
                    float gv = tanh_fast(acc[mi][2][r] + bg);
                    float ov = sigf(acc[mi][3][r] + bo);
                    float cnew = fv * c_reg[mi][r] + iv * gv;
                    c_reg[mi][r] = cnew;
                    float hv = ov * tanh_fast(cnew);
                    int row = mi * 16 + o * 4 + r;
                    int gs_h = h_g ^ ((row >> 1) & 3);
                    *(unsigned short*)(smem + HA_OFF + h_chunk * 5120 + row * 64 + gs_h * 16 + h_j * 2) = f2b_rn(hv);
                }
        } else {
            // final step: fuse FC.  partial = h * fc_w[col]; reduce over 16 cols via shfl, stash per wave.
#pragma unroll
            for (int mi = 0; mi < 5; ++mi)
#pragma unroll
                for (int r = 0; r < 4; ++r) {
                    float iv = sigf(acc[mi][0][r] + bi);
                    float fv = sigf(acc[mi][1][r] + bff);
                    float gv = tanh_fast(acc[mi][2][r] + bg);
                    float ov = sigf(acc[mi][3][r] + bo);
                    float cnew = fv * c_reg[mi][r] + iv * gv;
                    float hv = ov * tanh_fast(cnew);
                    float p = hv * fcw;
                    p += __shfl_xor(p, 1);
                    p += __shfl_xor(p, 2);
                    p += __shfl_xor(p, 4);
                    p += __shfl_xor(p, 8);
                    if (l15 == 0) {
                        int row = mi * 16 + o * 4 + r;
                        ((float*)(smem + RED_OFF))[w * 80 + row] = p;
                    }
                }
        }
    }
    __syncthreads();
    if (tid < 80) {
        const float* red = (const float*)(smem + RED_OFF);
        float s = 0.f;
#pragma unroll
        for (int w8 = 0; w8 < 8; ++w8) s += red[w8 * 80 + tid];
        out[base + tid] = s + fc_b[0];
    }
}

// ---------------- host ----------------

extern "C" void kernel_launch(void* const* d_in, const int* in_sizes, int n_in,
                              void* d_out, int out_size, void* d_ws, size_t ws_size,
                              hipStream_t stream) {
    const float* x_seq = (const float*)d_in[0];
    const int* edge = (const int*)d_in[1];
    const float* gcn_w = (const float*)d_in[2];
    const float* gcn_b = (const float*)d_in[3];
    const float* w_ih = (const float*)d_in[4];
    const float* w_hh = (const float*)d_in[5];
    const float* b_ih = (const float*)d_in[6];
    const float* b_hh = (const float*)d_in[7];
    const float* fc_w = (const float*)d_in[8];
    const float* fc_b = (const float*)d_in[9];
    float* out = (float*)d_out;

    char* w = (char*)d_ws;
    auto carve = [&](size_t bytes) {
        void* p = (void*)w;
        w += (bytes + 255) & ~(size_t)255;
        return p;
    };
    float* dinv = (float*)carve(NN * 4);
    int* deg = (int*)carve(NN * 4);
    int* row_ptr = (int*)carve((NN + 1) * 4);
    int* cursor = (int*)carve(NN * 4);
    int* csr_src = (int*)carve(NE * 4);
    float* csr_norm = (float*)carve(NE * 4);
    unsigned short* xwb = (unsigned short*)carve((size_t)TOTAL * GH * 2);
    unsigned short* hs_b = (unsigned short*)carve((size_t)TOTAL * GH * 2);
    unsigned short* wp = (unsigned short*)carve((size_t)6 * 512 * 4 * 8 * 2);
    unsigned short* wx = (unsigned short*)carve((size_t)4 * 64 * 4 * 8 * 2);
    float* bias = (float*)carve(512 * 4);

    hipMemsetAsync(deg, 0, NN * 4, stream);

    const int* e_src = edge;
    const int* e_dst = edge + NE;

    degree_kernel<<<(NE + 255) / 256, 256, 0, stream>>>(e_dst, deg);
    dinv_kernel<<<(NN + 255) / 256, 256, 0, stream>>>(deg, dinv);
    scan_kernel<<<1, 1024, 0, stream>>>(deg, row_ptr, cursor);
    scatter_kernel<<<(NE + 255) / 256, 256, 0, stream>>>(e_src, e_dst, dinv, cursor, csr_src, csr_norm);

    wprep_lstm_kernel<<<(6 * 512 * 4 + 255) / 256, 256, 0, stream>>>(w_ih, w_hh, wp);
    wprep_gcn_kernel<<<(4 * 64 * 4 + 255) / 256, 256, 0, stream>>>(gcn_w, wx);
    bias_kernel<<<2, 256, 0, stream>>>(b_ih, b_hh, bias);

    xw_mfma_kernel<<<TOTAL / 64, 256, 0, stream>>>(x_seq, wx, xwb);
    dim3 ggrid(NN / 4, TT);
    gather_kernel<<<ggrid, 256, 0, stream>>>(xwb, dinv, row_ptr, csr_src, csr_norm, gcn_b, hs_b);
    lstm_persist_kernel<<<NN / 80, 512, 0, stream>>>(hs_b, wp, bias, fc_w, fc_b, out);
}

// Round 4
// 314.032 us; speedup vs baseline: 5.7244x; 1.6518x over previous
//
#include <hip/hip_runtime.h>

// Problem constants (GNNRNNModel_18270790877883)
constexpr int NN = 20000;   // nodes
constexpr int NE = 320000;  // edges
constexpr int TT = 12;      // timesteps
constexpr int CIN = 128;    // in channels
constexpr int GH = 64;      // gnn hidden
constexpr int RH = 128;     // rnn hidden
constexpr int TOTAL = TT * NN;  // 240000

typedef __attribute__((ext_vector_type(8))) short short8;
typedef __attribute__((ext_vector_type(4))) float f32x4;

__device__ __forceinline__ float sigf(float x) { return 1.0f / (1.0f + __expf(-x)); }
__device__ __forceinline__ float tanh_fast(float x) { return 1.0f - 2.0f / (__expf(2.0f * x) + 1.0f); }

__device__ __forceinline__ unsigned short f2b_rn(float x) {
    union { float f; unsigned int u; } v; v.f = x;
    unsigned int r = v.u + 0x7FFFu + ((v.u >> 16) & 1u);
    return (unsigned short)(r >> 16);
}
__device__ __forceinline__ float b2f(unsigned short b) {
    union { unsigned int u; float f; } v; v.u = ((unsigned int)b) << 16;
    return v.f;
}

__device__ __forceinline__ void gload_lds16(const void* g, void* l) {
    __builtin_amdgcn_global_load_lds((const __attribute__((address_space(1))) void*)g,
                                     (__attribute__((address_space(3))) void*)l, 16, 0, 0);
}

// ---------------- graph preprocessing ----------------

__global__ __launch_bounds__(256) void degree_kernel(const int* __restrict__ dst, int* __restrict__ deg) {
    int e = blockIdx.x * blockDim.x + threadIdx.x;
    if (e < NE) atomicAdd(&deg[dst[e]], 1);
}

__global__ __launch_bounds__(256) void dinv_kernel(const int* __restrict__ deg, float* __restrict__ dinv) {
    int n = blockIdx.x * blockDim.x + threadIdx.x;
    if (n < NN) dinv[n] = rsqrtf((float)deg[n] + 1.0f);  // +1 self loop
}

__global__ __launch_bounds__(1024) void scan_kernel(const int* __restrict__ deg, int* __restrict__ row_ptr,
                                                    int* __restrict__ cursor) {
    __shared__ int sums[1024];
    int t = threadIdx.x;
    const int per = (NN + 1023) / 1024;
    int start = t * per;
    int end = min(start + per, NN);
    int s = 0;
    for (int i = start; i < end; ++i) s += deg[i];
    sums[t] = s;
    __syncthreads();
    for (int off = 1; off < 1024; off <<= 1) {
        int v = (t >= off) ? sums[t - off] : 0;
        __syncthreads();
        sums[t] += v;
        __syncthreads();
    }
    int run = (t == 0) ? 0 : sums[t - 1];
    for (int i = start; i < end; ++i) {
        row_ptr[i] = run;
        cursor[i] = run;
        run += deg[i];
    }
    if (t == 1023) row_ptr[NN] = sums[1023];
}

__global__ __launch_bounds__(256) void scatter_kernel(const int* __restrict__ src, const int* __restrict__ dst,
                                                      const float* __restrict__ dinv, int* __restrict__ cursor,
                                                      int* __restrict__ csr_src, float* __restrict__ csr_norm) {
    int e = blockIdx.x * blockDim.x + threadIdx.x;
    if (e >= NE) return;
    int d = dst[e], s = src[e];
    int pos = atomicAdd(&cursor[d], 1);
    csr_src[pos] = s;
    csr_norm[pos] = dinv[s] * dinv[d];
}

// ---------------- weight prep (bf16, XOR-swizzled granule layout) ----------------
// wp[(chunk*512 + col)*4 + gs] (granule of 8 bf16) holds WT[col][k],
//   k = chunk*32 + (gs ^ ((col>>1)&3))*8 + j ;  WT[col][k] = k<64 ? w_ih[col][k] : w_hh[col][k-64]

__global__ __launch_bounds__(256) void wprep_lstm_kernel(const float* __restrict__ w_ih, const float* __restrict__ w_hh,
                                                         unsigned short* __restrict__ wp) {
    int gidx = blockIdx.x * blockDim.x + threadIdx.x;  // granule id
    if (gidx >= 6 * 512 * 4) return;
    int gs = gidx & 3;
    int col = (gidx >> 2) & 511;
    int chunk = gidx >> 11;
    int g = gs ^ ((col >> 1) & 3);
    int k0 = chunk * 32 + g * 8;
    short8 v;
#pragma unroll
    for (int j = 0; j < 8; ++j) {
        int k = k0 + j;
        float f = (k < 64) ? w_ih[col * 64 + k] : w_hh[col * 128 + (k - 64)];
        v[j] = (short)f2b_rn(f);
    }
    *reinterpret_cast<short8*>(wp + (size_t)gidx * 8) = v;
}

// GCN weight: wx[(chunk*64 + col)*4 + gs] = gcn_w[k][col], k = chunk*32 + (gs ^ ((col>>1)&3))*8 + j
__global__ __launch_bounds__(256) void wprep_gcn_kernel(const float* __restrict__ gcn_w, unsigned short* __restrict__ wx) {
    int gidx = blockIdx.x * blockDim.x + threadIdx.x;
    if (gidx >= 4 * 64 * 4) return;
    int gs = gidx & 3;
    int col = (gidx >> 2) & 63;
    int chunk = gidx >> 8;
    int g = gs ^ ((col >> 1) & 3);
    int k0 = chunk * 32 + g * 8;
    short8 v;
#pragma unroll
    for (int j = 0; j < 8; ++j) v[j] = (short)f2b_rn(gcn_w[(k0 + j) * 64 + col]);
    *reinterpret_cast<short8*>(wx + (size_t)gidx * 8) = v;
}

__global__ __launch_bounds__(256) void bias_kernel(const float* __restrict__ b_ih, const float* __restrict__ b_hh,
                                                   float* __restrict__ bias) {
    int i = blockIdx.x * blockDim.x + threadIdx.x;
    if (i < 4 * RH) bias[i] = b_ih[i] + b_hh[i];
}

// ---------------- batched XW: bf16 MFMA GEMM  M=240000 K=128 N=64, bf16 out ----------------

__global__ __launch_bounds__(256) void xw_mfma_kernel(const float* __restrict__ x,          // [TOTAL,128]
                                                      const unsigned short* __restrict__ wx,
                                                      unsigned short* __restrict__ xwb) {   // [TOTAL,64] bf16
    __shared__ __align__(16) char As[4 * 4096];  // [chunk][64 rows][4 gs][16B]
    __shared__ __align__(16) char Bs[4 * 4096];  // [chunk][64 cols][4 gs][16B]
    int tid = threadIdx.x;
    int lane = tid & 63, w = tid >> 6;
    int m0 = blockIdx.x * 64;

#pragma unroll
    for (int j = 0; j < 4; ++j) {
        const unsigned short* src = wx + (size_t)(w * 4 + j) * 512 + lane * 8;
        gload_lds16(src, Bs + (w * 4 + j) * 1024);
    }
    {
        int row = tid >> 2, gs = tid & 3;
        int srow = m0 + row;
        int g = gs ^ ((row >> 1) & 3);
        const float* sp = x + (size_t)srow * CIN + g * 8;
#pragma unroll
        for (int c = 0; c < 4; ++c) {
            float4 f0 = *reinterpret_cast<const float4*>(sp + c * 32);
            float4 f1 = *reinterpret_cast<const float4*>(sp + c * 32 + 4);
            short8 v;
            v[0] = (short)f2b_rn(f0.x); v[1] = (short)f2b_rn(f0.y);
            v[2] = (short)f2b_rn(f0.z); v[3] = (short)f2b_rn(f0.w);
            v[4] = (short)f2b_rn(f1.x); v[5] = (short)f2b_rn(f1.y);
            v[6] = (short)f2b_rn(f1.z); v[7] = (short)f2b_rn(f1.w);
            *reinterpret_cast<short8*>(As + c * 4096 + row * 64 + gs * 16) = v;
        }
    }
    __syncthreads();

    f32x4 acc[4] = {};
    int rl = w * 16 + (lane & 15);
    int o = lane >> 4;
#pragma unroll
    for (int c = 0; c < 4; ++c) {
        int gsa = o ^ ((rl >> 1) & 3);
        short8 a = *reinterpret_cast<const short8*>(As + c * 4096 + rl * 64 + gsa * 16);
#pragma unroll
        for (int cn = 0; cn < 4; ++cn) {
            int col = cn * 16 + (lane & 15);
            int gsb = o ^ ((col >> 1) & 3);
            short8 b = *reinterpret_cast<const short8*>(Bs + c * 4096 + col * 64 + gsb * 16);
            acc[cn] = __builtin_amdgcn_mfma_f32_16x16x32_bf16(a, b, acc[cn], 0, 0, 0);
        }
    }
#pragma unroll
    for (int cn = 0; cn < 4; ++cn)
#pragma unroll
        for (int r = 0; r < 4; ++r) {
            int row = m0 + w * 16 + (lane >> 4) * 4 + r;
            int col = cn * 16 + (lane & 15);
            xwb[(size_t)row * GH + col] = f2b_rn(acc[cn][r]);
        }
}

// ---------------- batched GCN aggregation: wave per (node,t); batched indices + 8-wide ILP ----------------

__global__ __launch_bounds__(256) void gather_kernel(const unsigned short* __restrict__ xwb, const float* __restrict__ dinv,
                                                     const int* __restrict__ row_ptr, const int* __restrict__ csr_src,
                                                     const float* __restrict__ csr_norm, const float* __restrict__ gcn_b,
                                                     unsigned short* __restrict__ hs_b) {
    int t = blockIdx.y;
    int wid = (blockIdx.x * blockDim.x + threadIdx.x) >> 6;
    int lane = threadIdx.x & 63;
    if (wid >= NN) return;
    const unsigned short* slice = xwb + (size_t)t * NN * GH;
    float dv = dinv[wid];
    float acc = gcn_b[lane] + dv * dv * b2f(slice[(size_t)wid * GH + lane]);
    int e0 = row_ptr[wid], e1 = row_ptr[wid + 1];
    int deg = e1 - e0;
    for (int base = 0; base < deg; base += 64) {
        int cnt = min(deg - base, 64);
        bool valid = lane < cnt;
        int myidx = valid ? csr_src[e0 + base + lane] : 0;
        float mynm = valid ? csr_norm[e0 + base + lane] : 0.f;
        int cnt8 = (cnt + 7) & ~7;  // pad lanes contribute 0 (mynm=0)
        for (int j = 0; j < cnt8; j += 8) {
            int s0 = __shfl(myidx, j + 0), s1 = __shfl(myidx, j + 1);
            int s2 = __shfl(myidx, j + 2), s3 = __shfl(myidx, j + 3);
            int s4 = __shfl(myidx, j + 4), s5 = __shfl(myidx, j + 5);
            int s6 = __shfl(myidx, j + 6), s7 = __shfl(myidx, j + 7);
            float n0 = __shfl(mynm, j + 0), n1 = __shfl(mynm, j + 1);
            float n2 = __shfl(mynm, j + 2), n3 = __shfl(mynm, j + 3);
            float n4 = __shfl(mynm, j + 4), n5 = __shfl(mynm, j + 5);
            float n6 = __shfl(mynm, j + 6), n7 = __shfl(mynm, j + 7);
            float v0 = b2f(slice[(size_t)s0 * GH + lane]);
            float v1 = b2f(slice[(size_t)s1 * GH + lane]);
            float v2 = b2f(slice[(size_t)s2 * GH + lane]);
            float v3 = b2f(slice[(size_t)s3 * GH + lane]);
            float v4 = b2f(slice[(size_t)s4 * GH + lane]);
            float v5 = b2f(slice[(size_t)s5 * GH + lane]);
            float v6 = b2f(slice[(size_t)s6 * GH + lane]);
            float v7 = b2f(slice[(size_t)s7 * GH + lane]);
            acc += n0 * v0; acc += n1 * v1; acc += n2 * v2; acc += n3 * v3;
            acc += n4 * v4; acc += n5 * v5; acc += n6 * v6; acc += n7 * v7;
        }
    }
    hs_b[((size_t)t * NN + wid) * GH + lane] = f2b_rn(acc);
}

// ---------------- persistent LSTM: 250 blocks x 512 thr; block owns 80 rows, loops all 12 steps ----------------
// Wave w owns rh-cols [w*16,w*16+16) of all 4 gates. c in regs; h via LDS (bf16, swizzled).
// B-fragments read directly from L2 (pre-swizzled wp -> 1KB coalesced segments). FC fused at t=11.

#define HS_OFF 0            // 2 slots x [2 chunks][80 rows][4 gs][16B] = 2 x 10240
#define HA_OFF 20480        // [4 chunks][80 rows][4 gs][16B] = 20480
#define RED_OFF 40960       // float [8][80] = 2560
#define SMEM_BYTES 43520

__global__ __launch_bounds__(512, 2) void lstm_persist_kernel(const unsigned short* __restrict__ hs_all, // [TT,NN,64]
                                                              const unsigned short* __restrict__ wp,     // [6][512][4][8]
                                                              const float* __restrict__ bias,            // [512]
                                                              const float* __restrict__ fc_w,            // [128]
                                                              const float* __restrict__ fc_b,            // [1]
                                                              float* __restrict__ out) {                 // [NN]
    __shared__ __align__(16) char smem[SMEM_BYTES];
    int tid = threadIdx.x;
    int lane = tid & 63, w = tid >> 6;
    int l15 = lane & 15, o = lane >> 4;
    int base = blockIdx.x * 80;

    int sw = o ^ ((l15 >> 1) & 3);       // shared swizzle for all A reads and B reads
    int colbase = w * 16 + l15;          // this thread's rh-col
    float bi = bias[colbase], bff = bias[128 + colbase], bg = bias[256 + colbase], bo = bias[384 + colbase];
    float fcw = fc_w[colbase];

    // h-write constants: k = 64 + colbase -> chunk, granule, elem
    int h_chunk = w >> 1;                          // 0..3
    int h_g = ((w & 1) << 1) + (l15 >> 3);         // granule within 32-k chunk
    int h_j = l15 & 7;                             // elem within granule

    // prologue: zero h region, stage hs[0] into slot 0
    {
#pragma unroll
        for (int i = 0; i < 10; ++i) ((int*)(smem + HA_OFF))[tid + i * 512] = 0;
#pragma unroll
        for (int j = 0; j < 2; ++j) {
            int gi = j * 512 + tid;
            if (gi < 640) {
                int cc = (gi >= 320) ? 1 : 0;
                int rem = gi - cc * 320;
                int row = rem >> 2, gs = rem & 3;
                int g = gs ^ ((row >> 1) & 3);
                const unsigned short* src = hs_all + ((size_t)(base + row)) * 64 + cc * 32 + g * 8;
                gload_lds16(src, smem + HS_OFF + gi * 16);
            }
        }
    }

    float c_reg[5][4] = {};
    f32x4 acc[5][4];

#pragma unroll 1
    for (int t = 0; t < TT; ++t) {
        __syncthreads();  // drains vmcnt: hs[t] staged + prev h-writes visible

        // prefetch hs[t+1] into other slot
        if (t + 1 < TT) {
            char* dstb = smem + HS_OFF + ((t + 1) & 1) * 10240;
#pragma unroll
            for (int j = 0; j < 2; ++j) {
                int gi = j * 512 + tid;
                if (gi < 640) {
                    int cc = (gi >= 320) ? 1 : 0;
                    int rem = gi - cc * 320;
                    int row = rem >> 2, gs = rem & 3;
                    int g = gs ^ ((row >> 1) & 3);
                    const unsigned short* src = hs_all + ((size_t)(t + 1) * NN + base + row) * 64 + cc * 32 + g * 8;
                    gload_lds16(src, dstb + gi * 16);
                }
            }
        }

#pragma unroll
        for (int mi = 0; mi < 5; ++mi)
#pragma unroll
            for (int g = 0; g < 4; ++g) acc[mi][g] = (f32x4){0.f, 0.f, 0.f, 0.f};

        const char* hsb = smem + HS_OFF + (t & 1) * 10240;
#pragma unroll
        for (int c = 0; c < 6; ++c) {
            // B frags: direct from L2 (1KB coalesced per wave per (c,g))
            short8 b[4];
#pragma unroll
            for (int g = 0; g < 4; ++g) {
                size_t goff = ((size_t)(c * 512 + g * 128 + colbase) * 4 + sw) * 8;
                b[g] = *reinterpret_cast<const short8*>(wp + goff);
            }
            const char* abase = (c < 2) ? (hsb + c * 5120) : (smem + HA_OFF + (c - 2) * 5120);
            short8 a[5];
#pragma unroll
            for (int mi = 0; mi < 5; ++mi)
                a[mi] = *reinterpret_cast<const short8*>(abase + (mi * 16 + l15) * 64 + sw * 16);
#pragma unroll
            for (int g = 0; g < 4; ++g)
#pragma unroll
                for (int mi = 0; mi < 5; ++mi)
                    acc[mi][g] = __builtin_amdgcn_mfma_f32_16x16x32_bf16(a[mi], b[g], acc[mi][g], 0, 0, 0);
        }

        __syncthreads();  // all reads of h region done before overwrite

        // epilogue: thread covers rows mi*16 + o*4 + r, col = colbase
        if (t + 1 < TT) {
#pragma unroll
            for (int mi = 0; mi < 5; ++mi)
#pragma unroll
                for (int r = 0; r < 4; ++r) {
                    float iv = sigf(acc[mi][0][r] + bi);
                    float fv = sigf(acc[mi][1][r] + bff);
                    float gv = tanh_fast(acc[mi][2][r] + bg);
                    float ov = sigf(acc[mi][3][r] + bo);
                    float cnew = fv * c_reg[mi][r] + iv * gv;
                    c_reg[mi][r] = cnew;
                    float hv = ov * tanh_fast(cnew);
                    int row = mi * 16 + o * 4 + r;
                    int gs_h = h_g ^ ((row >> 1) & 3);
                    *(unsigned short*)(smem + HA_OFF + h_chunk * 5120 + row * 64 + gs_h * 16 + h_j * 2) = f2b_rn(hv);
                }
        } else {
            // final step: fuse FC.  partial = h * fc_w[col]; reduce over 16 cols via shfl, stash per wave.
#pragma unroll
            for (int mi = 0; mi < 5; ++mi)
#pragma unroll
                for (int r = 0; r < 4; ++r) {
                    float iv = sigf(acc[mi][0][r] + bi);
                    float fv = sigf(acc[mi][1][r] + bff);
                    float gv = tanh_fast(acc[mi][2][r] + bg);
                    float ov = sigf(acc[mi][3][r] + bo);
                    float cnew = fv * c_reg[mi][r] + iv * gv;
                    float hv = ov * tanh_fast(cnew);
                    float p = hv * fcw;
                    p += __shfl_xor(p, 1);
                    p += __shfl_xor(p, 2);
                    p += __shfl_xor(p, 4);
                    p += __shfl_xor(p, 8);
                    if (l15 == 0) {
                        int row = mi * 16 + o * 4 + r;
                        ((float*)(smem + RED_OFF))[w * 80 + row] = p;
                    }
                }
        }
    }
    __syncthreads();
    if (tid < 80) {
        const float* red = (const float*)(smem + RED_OFF);
        float s = 0.f;
#pragma unroll
        for (int w8 = 0; w8 < 8; ++w8) s += red[w8 * 80 + tid];
        out[base + tid] = s + fc_b[0];
    }
}

// ---------------- host ----------------

extern "C" void kernel_launch(void* const* d_in, const int* in_sizes, int n_in,
                              void* d_out, int out_size, void* d_ws, size_t ws_size,
                              hipStream_t stream) {
    const float* x_seq = (const float*)d_in[0];
    const int* edge = (const int*)d_in[1];
    const float* gcn_w = (const float*)d_in[2];
    const float* gcn_b = (const float*)d_in[3];
    const float* w_ih = (const float*)d_in[4];
    const float* w_hh = (const float*)d_in[5];
    const float* b_ih = (const float*)d_in[6];
    const float* b_hh = (const float*)d_in[7];
    const float* fc_w = (const float*)d_in[8];
    const float* fc_b = (const float*)d_in[9];
    float* out = (float*)d_out;

    char* w = (char*)d_ws;
    auto carve = [&](size_t bytes) {
        void* p = (void*)w;
        w += (bytes + 255) & ~(size_t)255;
        return p;
    };
    float* dinv = (float*)carve(NN * 4);
    int* deg = (int*)carve(NN * 4);
    int* row_ptr = (int*)carve((NN + 1) * 4);
    int* cursor = (int*)carve(NN * 4);
    int* csr_src = (int*)carve(NE * 4);
    float* csr_norm = (float*)carve(NE * 4);
    unsigned short* xwb = (unsigned short*)carve((size_t)TOTAL * GH * 2);
    unsigned short* hs_b = (unsigned short*)carve((size_t)TOTAL * GH * 2);
    unsigned short* wp = (unsigned short*)carve((size_t)6 * 512 * 4 * 8 * 2);
    unsigned short* wx = (unsigned short*)carve((size_t)4 * 64 * 4 * 8 * 2);
    float* bias = (float*)carve(512 * 4);

    hipMemsetAsync(deg, 0, NN * 4, stream);

    const int* e_src = edge;
    const int* e_dst = edge + NE;

    degree_kernel<<<(NE + 255) / 256, 256, 0, stream>>>(e_dst, deg);
    dinv_kernel<<<(NN + 255) / 256, 256, 0, stream>>>(deg, dinv);
    scan_kernel<<<1, 1024, 0, stream>>>(deg, row_ptr, cursor);
    scatter_kernel<<<(NE + 255) / 256, 256, 0, stream>>>(e_src, e_dst, dinv, cursor, csr_src, csr_norm);

    wprep_lstm_kernel<<<(6 * 512 * 4 + 255) / 256, 256, 0, stream>>>(w_ih, w_hh, wp);
    wprep_gcn_kernel<<<(4 * 64 * 4 + 255) / 256, 256, 0, stream>>>(gcn_w, wx);
    bias_kernel<<<2, 256, 0, stream>>>(b_ih, b_hh, bias);

    xw_mfma_kernel<<<TOTAL / 64, 256, 0, stream>>>(x_seq, wx, xwb);
    dim3 ggrid(NN / 4, TT);
    gather_kernel<<<ggrid, 256, 0, stream>>>(xwb, dinv, row_ptr, csr_src, csr_norm, gcn_b, hs_b);
    lstm_persist_kernel<<<NN / 80, 512, 0, stream>>>(hs_b, wp, bias, fc_w, fc_b, out);
}

// Round 5
// 285.458 us; speedup vs baseline: 6.2974x; 1.1001x over previous
//
#include <hip/hip_runtime.h>

// Problem constants (GNNRNNModel_18270790877883)
constexpr int NN = 20000;   // nodes
constexpr int NE = 320000;  // edges
constexpr int TT = 12;      // timesteps
constexpr int CIN = 128;    // in channels
constexpr int GH = 64;      // gnn hidden
constexpr int RH = 128;     // rnn hidden
constexpr int TOTAL = TT * NN;  // 240000

typedef __attribute__((ext_vector_type(8))) short short8;
typedef __attribute__((ext_vector_type(4))) float f32x4;

__device__ __forceinline__ float sigf(float x) { return 1.0f / (1.0f + __expf(-x)); }
__device__ __forceinline__ float tanh_fast(float x) { return 1.0f - 2.0f / (__expf(2.0f * x) + 1.0f); }

__device__ __forceinline__ unsigned short f2b_rn(float x) {
    union { float f; unsigned int u; } v; v.f = x;
    unsigned int r = v.u + 0x7FFFu + ((v.u >> 16) & 1u);
    return (unsigned short)(r >> 16);
}
__device__ __forceinline__ float b2f(unsigned short b) {
    union { unsigned int u; float f; } v; v.u = ((unsigned int)b) << 16;
    return v.f;
}

__device__ __forceinline__ void gload_lds16(const void* g, void* l) {
    __builtin_amdgcn_global_load_lds((const __attribute__((address_space(1))) void*)g,
                                     (__attribute__((address_space(3))) void*)l, 16, 0, 0);
}

// ---------------- graph preprocessing ----------------

__global__ __launch_bounds__(256) void degree_kernel(const int* __restrict__ dst, int* __restrict__ deg) {
    int e = blockIdx.x * blockDim.x + threadIdx.x;
    if (e < NE) atomicAdd(&deg[dst[e]], 1);
}

__global__ __launch_bounds__(256) void dinv_kernel(const int* __restrict__ deg, float* __restrict__ dinv) {
    int n = blockIdx.x * blockDim.x + threadIdx.x;
    if (n < NN) dinv[n] = rsqrtf((float)deg[n] + 1.0f);  // +1 self loop
}

__global__ __launch_bounds__(1024) void scan_kernel(const int* __restrict__ deg, int* __restrict__ row_ptr,
                                                    int* __restrict__ cursor) {
    __shared__ int sums[1024];
    int t = threadIdx.x;
    const int per = (NN + 1023) / 1024;
    int start = t * per;
    int end = min(start + per, NN);
    int s = 0;
    for (int i = start; i < end; ++i) s += deg[i];
    sums[t] = s;
    __syncthreads();
    for (int off = 1; off < 1024; off <<= 1) {
        int v = (t >= off) ? sums[t - off] : 0;
        __syncthreads();
        sums[t] += v;
        __syncthreads();
    }
    int run = (t == 0) ? 0 : sums[t - 1];
    for (int i = start; i < end; ++i) {
        row_ptr[i] = run;
        cursor[i] = run;
        run += deg[i];
    }
    if (t == 1023) row_ptr[NN] = sums[1023];
}

__global__ __launch_bounds__(256) void scatter_kernel(const int* __restrict__ src, const int* __restrict__ dst,
                                                      const float* __restrict__ dinv, int* __restrict__ cursor,
                                                      int* __restrict__ csr_src, float* __restrict__ csr_norm) {
    int e = blockIdx.x * blockDim.x + threadIdx.x;
    if (e >= NE) return;
    int d = dst[e], s = src[e];
    int pos = atomicAdd(&cursor[d], 1);
    csr_src[pos] = s;
    csr_norm[pos] = dinv[s] * dinv[d];
}

// ---------------- weight prep (bf16, XOR-swizzled granule layout) ----------------
// wp[(chunk*512 + col)*4 + gs] (granule of 8 bf16) holds WT[col][k],
//   k = chunk*32 + (gs ^ ((col>>1)&3))*8 + j ;  WT[col][k] = k<64 ? w_ih[col][k] : w_hh[col][k-64]

__global__ __launch_bounds__(256) void wprep_lstm_kernel(const float* __restrict__ w_ih, const float* __restrict__ w_hh,
                                                         unsigned short* __restrict__ wp) {
    int gidx = blockIdx.x * blockDim.x + threadIdx.x;  // granule id
    if (gidx >= 6 * 512 * 4) return;
    int gs = gidx & 3;
    int col = (gidx >> 2) & 511;
    int chunk = gidx >> 11;
    int g = gs ^ ((col >> 1) & 3);
    int k0 = chunk * 32 + g * 8;
    short8 v;
#pragma unroll
    for (int j = 0; j < 8; ++j) {
        int k = k0 + j;
        float f = (k < 64) ? w_ih[col * 64 + k] : w_hh[col * 128 + (k - 64)];
        v[j] = (short)f2b_rn(f);
    }
    *reinterpret_cast<short8*>(wp + (size_t)gidx * 8) = v;
}

// GCN weight: wx[(chunk*64 + col)*4 + gs] = gcn_w[k][col], k = chunk*32 + (gs ^ ((col>>1)&3))*8 + j
__global__ __launch_bounds__(256) void wprep_gcn_kernel(const float* __restrict__ gcn_w, unsigned short* __restrict__ wx) {
    int gidx = blockIdx.x * blockDim.x + threadIdx.x;
    if (gidx >= 4 * 64 * 4) return;
    int gs = gidx & 3;
    int col = (gidx >> 2) & 63;
    int chunk = gidx >> 8;
    int g = gs ^ ((col >> 1) & 3);
    int k0 = chunk * 32 + g * 8;
    short8 v;
#pragma unroll
    for (int j = 0; j < 8; ++j) v[j] = (short)f2b_rn(gcn_w[(k0 + j) * 64 + col]);
    *reinterpret_cast<short8*>(wx + (size_t)gidx * 8) = v;
}

__global__ __launch_bounds__(256) void bias_kernel(const float* __restrict__ b_ih, const float* __restrict__ b_hh,
                                                   float* __restrict__ bias) {
    int i = blockIdx.x * blockDim.x + threadIdx.x;
    if (i < 4 * RH) bias[i] = b_ih[i] + b_hh[i];
}

// ---------------- batched XW: bf16 MFMA GEMM  M=240000 K=128 N=64, bf16 out ----------------

__global__ __launch_bounds__(256) void xw_mfma_kernel(const float* __restrict__ x,          // [TOTAL,128]
                                                      const unsigned short* __restrict__ wx,
                                                      unsigned short* __restrict__ xwb) {   // [TOTAL,64] bf16
    __shared__ __align__(16) char As[4 * 4096];  // [chunk][64 rows][4 gs][16B]
    __shared__ __align__(16) char Bs[4 * 4096];  // [chunk][64 cols][4 gs][16B]
    int tid = threadIdx.x;
    int lane = tid & 63, w = tid >> 6;
    int m0 = blockIdx.x * 64;

#pragma unroll
    for (int j = 0; j < 4; ++j) {
        const unsigned short* src = wx + (size_t)(w * 4 + j) * 512 + lane * 8;
        gload_lds16(src, Bs + (w * 4 + j) * 1024);
    }
    {
        int row = tid >> 2, gs = tid & 3;
        int srow = m0 + row;
        int g = gs ^ ((row >> 1) & 3);
        const float* sp = x + (size_t)srow * CIN + g * 8;
#pragma unroll
        for (int c = 0; c < 4; ++c) {
            float4 f0 = *reinterpret_cast<const float4*>(sp + c * 32);
            float4 f1 = *reinterpret_cast<const float4*>(sp + c * 32 + 4);
            short8 v;
            v[0] = (short)f2b_rn(f0.x); v[1] = (short)f2b_rn(f0.y);
            v[2] = (short)f2b_rn(f0.z); v[3] = (short)f2b_rn(f0.w);
            v[4] = (short)f2b_rn(f1.x); v[5] = (short)f2b_rn(f1.y);
            v[6] = (short)f2b_rn(f1.z); v[7] = (short)f2b_rn(f1.w);
            *reinterpret_cast<short8*>(As + c * 4096 + row * 64 + gs * 16) = v;
        }
    }
    __syncthreads();

    f32x4 acc[4] = {};
    int rl = w * 16 + (lane & 15);
    int o = lane >> 4;
#pragma unroll
    for (int c = 0; c < 4; ++c) {
        int gsa = o ^ ((rl >> 1) & 3);
        short8 a = *reinterpret_cast<const short8*>(As + c * 4096 + rl * 64 + gsa * 16);
#pragma unroll
        for (int cn = 0; cn < 4; ++cn) {
            int col = cn * 16 + (lane & 15);
            int gsb = o ^ ((col >> 1) & 3);
            short8 b = *reinterpret_cast<const short8*>(Bs + c * 4096 + col * 64 + gsb * 16);
            acc[cn] = __builtin_amdgcn_mfma_f32_16x16x32_bf16(a, b, acc[cn], 0, 0, 0);
        }
    }
#pragma unroll
    for (int cn = 0; cn < 4; ++cn)
#pragma unroll
        for (int r = 0; r < 4; ++r) {
            int row = m0 + w * 16 + (lane >> 4) * 4 + r;
            int col = cn * 16 + (lane & 15);
            xwb[(size_t)row * GH + col] = f2b_rn(acc[cn][r]);
        }
}

// ---------------- batched GCN aggregation: wave per node x 2 timesteps; shared indices, 16-wide ILP ----------------

__global__ __launch_bounds__(256) void gather_kernel(const unsigned short* __restrict__ xwb, const float* __restrict__ dinv,
                                                     const int* __restrict__ row_ptr, const int* __restrict__ csr_src,
                                                     const float* __restrict__ csr_norm, const float* __restrict__ gcn_b,
                                                     unsigned short* __restrict__ hs_b) {
    int t0 = blockIdx.y * 2;
    int wid = (blockIdx.x * blockDim.x + threadIdx.x) >> 6;
    int lane = threadIdx.x & 63;
    if (wid >= NN) return;
    const unsigned short* sl0 = xwb + (size_t)t0 * NN * GH;
    const unsigned short* sl1 = sl0 + (size_t)NN * GH;
    float dv = dinv[wid];
    float bsv = gcn_b[lane];
    float acc0 = bsv + dv * dv * b2f(sl0[(size_t)wid * GH + lane]);
    float acc1 = bsv + dv * dv * b2f(sl1[(size_t)wid * GH + lane]);
    int e0 = row_ptr[wid], e1 = row_ptr[wid + 1];
    int deg = e1 - e0;
    for (int base = 0; base < deg; base += 64) {
        int cnt = min(deg - base, 64);
        bool valid = lane < cnt;
        int myidx = valid ? csr_src[e0 + base + lane] : 0;
        float mynm = valid ? csr_norm[e0 + base + lane] : 0.f;
        int cnt8 = (cnt + 7) & ~7;  // pad lanes contribute 0 (mynm=0)
        for (int j = 0; j < cnt8; j += 8) {
            int s0 = __shfl(myidx, j + 0), s1 = __shfl(myidx, j + 1);
            int s2 = __shfl(myidx, j + 2), s3 = __shfl(myidx, j + 3);
            int s4 = __shfl(myidx, j + 4), s5 = __shfl(myidx, j + 5);
            int s6 = __shfl(myidx, j + 6), s7 = __shfl(myidx, j + 7);
            float n0 = __shfl(mynm, j + 0), n1 = __shfl(mynm, j + 1);
            float n2 = __shfl(mynm, j + 2), n3 = __shfl(mynm, j + 3);
            float n4 = __shfl(mynm, j + 4), n5 = __shfl(mynm, j + 5);
            float n6 = __shfl(mynm, j + 6), n7 = __shfl(mynm, j + 7);
            float a0 = b2f(sl0[(size_t)s0 * GH + lane]);
            float a1 = b2f(sl0[(size_t)s1 * GH + lane]);
            float a2 = b2f(sl0[(size_t)s2 * GH + lane]);
            float a3 = b2f(sl0[(size_t)s3 * GH + lane]);
            float a4 = b2f(sl0[(size_t)s4 * GH + lane]);
            float a5 = b2f(sl0[(size_t)s5 * GH + lane]);
            float a6 = b2f(sl0[(size_t)s6 * GH + lane]);
            float a7 = b2f(sl0[(size_t)s7 * GH + lane]);
            float c0 = b2f(sl1[(size_t)s0 * GH + lane]);
            float c1 = b2f(sl1[(size_t)s1 * GH + lane]);
            float c2 = b2f(sl1[(size_t)s2 * GH + lane]);
            float c3 = b2f(sl1[(size_t)s3 * GH + lane]);
            float c4 = b2f(sl1[(size_t)s4 * GH + lane]);
            float c5 = b2f(sl1[(size_t)s5 * GH + lane]);
            float c6 = b2f(sl1[(size_t)s6 * GH + lane]);
            float c7 = b2f(sl1[(size_t)s7 * GH + lane]);
            acc0 += n0 * a0; acc0 += n1 * a1; acc0 += n2 * a2; acc0 += n3 * a3;
            acc0 += n4 * a4; acc0 += n5 * a5; acc0 += n6 * a6; acc0 += n7 * a7;
            acc1 += n0 * c0; acc1 += n1 * c1; acc1 += n2 * c2; acc1 += n3 * c3;
            acc1 += n4 * c4; acc1 += n5 * c5; acc1 += n6 * c6; acc1 += n7 * c7;
        }
    }
    hs_b[((size_t)t0 * NN + wid) * GH + lane] = f2b_rn(acc0);
    hs_b[((size_t)(t0 + 1) * NN + wid) * GH + lane] = f2b_rn(acc1);
}

// ---------------- persistent LSTM: 250 blocks x 512 thr; block owns 80 rows, loops all 12 steps ----------------
// Wave w owns rh-cols [w*16,w*16+16) of all 4 gates. c in regs; h via LDS (bf16, swizzled).
// B-fragments hoisted into 96 VGPRs before the t-loop (loop-invariant). FC fused at t=11.

#define HS_OFF 0            // 2 slots x [2 chunks][80 rows][4 gs][16B] = 2 x 10240
#define HA_OFF 20480        // [4 chunks][80 rows][4 gs][16B] = 20480
#define RED_OFF 40960       // float [8][80] = 2560
#define SMEM_BYTES 43520

__global__ __launch_bounds__(512, 2) void lstm_persist_kernel(const unsigned short* __restrict__ hs_all, // [TT,NN,64]
                                                              const unsigned short* __restrict__ wp,     // [6][512][4][8]
                                                              const float* __restrict__ bias,            // [512]
                                                              const float* __restrict__ fc_w,            // [128]
                                                              const float* __restrict__ fc_b,            // [1]
                                                              float* __restrict__ out) {                 // [NN]
    __shared__ __align__(16) char smem[SMEM_BYTES];
    int tid = threadIdx.x;
    int lane = tid & 63, w = tid >> 6;
    int l15 = lane & 15, o = lane >> 4;
    int base = blockIdx.x * 80;

    int sw = o ^ ((l15 >> 1) & 3);       // shared swizzle for all A reads (and B prep layout)
    int colbase = w * 16 + l15;          // this thread's rh-col
    float bi = bias[colbase], bff = bias[128 + colbase], bg = bias[256 + colbase], bo = bias[384 + colbase];
    float fcw = fc_w[colbase];

    // h-write constants: k = 64 + colbase -> chunk, granule, elem
    int h_chunk = w >> 1;                          // 0..3
    int h_g = ((w & 1) << 1) + (l15 >> 3);         // granule within 32-k chunk
    int h_j = l15 & 7;                             // elem within granule

    // hoist ALL B fragments into registers: 6 chunks x 4 gates x 16B = 96 VGPRs, loop-invariant
    short8 breg[6][4];
#pragma unroll
    for (int c = 0; c < 6; ++c)
#pragma unroll
        for (int g = 0; g < 4; ++g) {
            size_t goff = ((size_t)(c * 512 + g * 128 + colbase) * 4 + sw) * 8;
            breg[c][g] = *reinterpret_cast<const short8*>(wp + goff);
        }

    // prologue: zero h region, stage hs[0] into slot 0
    {
#pragma unroll
        for (int i = 0; i < 10; ++i) ((int*)(smem + HA_OFF))[tid + i * 512] = 0;
#pragma unroll
        for (int j = 0; j < 2; ++j) {
            int gi = j * 512 + tid;
            if (gi < 640) {
                int cc = (gi >= 320) ? 1 : 0;
                int rem = gi - cc * 320;
                int row = rem >> 2, gs = rem & 3;
                int g = gs ^ ((row >> 1) & 3);
                const unsigned short* src = hs_all + ((size_t)(base + row)) * 64 + cc * 32 + g * 8;
                gload_lds16(src, smem + HS_OFF + gi * 16);
            }
        }
    }

    float c_reg[5][4] = {};
    f32x4 acc[5][4];

#pragma unroll 1
    for (int t = 0; t < TT; ++t) {
        __syncthreads();  // drains vmcnt: hs[t] staged + prev h-writes visible

        // prefetch hs[t+1] into other slot
        if (t + 1 < TT) {
            char* dstb = smem + HS_OFF + ((t + 1) & 1) * 10240;
#pragma unroll
            for (int j = 0; j < 2; ++j) {
                int gi = j * 512 + tid;
                if (gi < 640) {
                    int cc = (gi >= 320) ? 1 : 0;
                    int rem = gi - cc * 320;
                    int row = rem >> 2, gs = rem & 3;
                    int g = gs ^ ((row >> 1) & 3);
                    const unsigned short* src = hs_all + ((size_t)(t + 1) * NN + base + row) * 64 + cc * 32 + g * 8;
                    gload_lds16(src, dstb + gi * 16);
                }
            }
        }

#pragma unroll
        for (int mi = 0; mi < 5; ++mi)
#pragma unroll
            for (int g = 0; g < 4; ++g) acc[mi][g] = (f32x4){0.f, 0.f, 0.f, 0.f};

        const char* hsb = smem + HS_OFF + (t & 1) * 10240;
#pragma unroll
        for (int c = 0; c < 6; ++c) {
            const char* abase = (c < 2) ? (hsb + c * 5120) : (smem + HA_OFF + (c - 2) * 5120);
            short8 a[5];
#pragma unroll
            for (int mi = 0; mi < 5; ++mi)
                a[mi] = *reinterpret_cast<const short8*>(abase + (mi * 16 + l15) * 64 + sw * 16);
#pragma unroll
            for (int g = 0; g < 4; ++g)
#pragma unroll
                for (int mi = 0; mi < 5; ++mi)
                    acc[mi][g] = __builtin_amdgcn_mfma_f32_16x16x32_bf16(a[mi], breg[c][g], acc[mi][g], 0, 0, 0);
        }

        __syncthreads();  // all reads of h region done before overwrite

        // epilogue: thread covers rows mi*16 + o*4 + r, col = colbase
        if (t + 1 < TT) {
#pragma unroll
            for (int mi = 0; mi < 5; ++mi)
#pragma unroll
                for (int r = 0; r < 4; ++r) {
                    float iv = sigf(acc[mi][0][r] + bi);
                    float fv = sigf(acc[mi][1][r] + bff);
                    float gv = tanh_fast(acc[mi][2][r] + bg);
                    float ov = sigf(acc[mi][3][r] + bo);
                    float cnew = fv * c_reg[mi][r] + iv * gv;
                    c_reg[mi][r] = cnew;
                    float hv = ov * tanh_fast(cnew);
                    int row = mi * 16 + o * 4 + r;
                    int gs_h = h_g ^ ((row >> 1) & 3);
                    *(unsigned short*)(smem + HA_OFF + h_chunk * 5120 + row * 64 + gs_h * 16 + h_j * 2) = f2b_rn(hv);
                }
        } else {
            // final step: fuse FC.  partial = h * fc_w[col]; reduce over 16 cols via shfl, stash per wave.
#pragma unroll
            for (int mi = 0; mi < 5; ++mi)
#pragma unroll
                for (int r = 0; r < 4; ++r) {
                    float iv = sigf(acc[mi][0][r] + bi);
                    float fv = sigf(acc[mi][1][r] + bff);
                    float gv = tanh_fast(acc[mi][2][r] + bg);
                    float ov = sigf(acc[mi][3][r] + bo);
                    float cnew = fv * c_reg[mi][r] + iv * gv;
                    float hv = ov * tanh_fast(cnew);
                    float p = hv * fcw;
                    p += __shfl_xor(p, 1);
                    p += __shfl_xor(p, 2);
                    p += __shfl_xor(p, 4);
                    p += __shfl_xor(p, 8);
                    if (l15 == 0) {
                        int row = mi * 16 + o * 4 + r;
                        ((float*)(smem + RED_OFF))[w * 80 + row] = p;
                    }
                }
        }
    }
    __syncthreads();
    if (tid < 80) {
        const float* red = (const float*)(smem + RED_OFF);
        float s = 0.f;
#pragma unroll
        for (int w8 = 0; w8 < 8; ++w8) s += red[w8 * 80 + tid];
        out[base + tid] = s + fc_b[0];
    }
}

// ---------------- host ----------------

extern "C" void kernel_launch(void* const* d_in, const int* in_sizes, int n_in,
                              void* d_out, int out_size, void* d_ws, size_t ws_size,
                              hipStream_t stream) {
    const float* x_seq = (const float*)d_in[0];
    const int* edge = (const int*)d_in[1];
    const float* gcn_w = (const float*)d_in[2];
    const float* gcn_b = (const float*)d_in[3];
    const float* w_ih = (const float*)d_in[4];
    const float* w_hh = (const float*)d_in[5];
    const float* b_ih = (const float*)d_in[6];
    const float* b_hh = (const float*)d_in[7];
    const float* fc_w = (const float*)d_in[8];
    const float* fc_b = (const float*)d_in[9];
    float* out = (float*)d_out;

    char* w = (char*)d_ws;
    auto carve = [&](size_t bytes) {
        void* p = (void*)w;
        w += (bytes + 255) & ~(size_t)255;
        return p;
    };
    float* dinv = (float*)carve(NN * 4);
    int* deg = (int*)carve(NN * 4);
    int* row_ptr = (int*)carve((NN + 1) * 4);
    int* cursor = (int*)carve(NN * 4);
    int* csr_src = (int*)carve(NE * 4);
    float* csr_norm = (float*)carve(NE * 4);
    unsigned short* xwb = (unsigned short*)carve((size_t)TOTAL * GH * 2);
    unsigned short* hs_b = (unsigned short*)carve((size_t)TOTAL * GH * 2);
    unsigned short* wp = (unsigned short*)carve((size_t)6 * 512 * 4 * 8 * 2);
    unsigned short* wx = (unsigned short*)carve((size_t)4 * 64 * 4 * 8 * 2);
    float* bias = (float*)carve(512 * 4);

    hipMemsetAsync(deg, 0, NN * 4, stream);

    const int* e_src = edge;
    const int* e_dst = edge + NE;

    degree_kernel<<<(NE + 255) / 256, 256, 0, stream>>>(e_dst, deg);
    dinv_kernel<<<(NN + 255) / 256, 256, 0, stream>>>(deg, dinv);
    scan_kernel<<<1, 1024, 0, stream>>>(deg, row_ptr, cursor);
    scatter_kernel<<<(NE + 255) / 256, 256, 0, stream>>>(e_src, e_dst, dinv, cursor, csr_src, csr_norm);

    wprep_lstm_kernel<<<(6 * 512 * 4 + 255) / 256, 256, 0, stream>>>(w_ih, w_hh, wp);
    wprep_gcn_kernel<<<(4 * 64 * 4 + 255) / 256, 256, 0, stream>>>(gcn_w, wx);
    bias_kernel<<<2, 256, 0, stream>>>(b_ih, b_hh, bias);

    xw_mfma_kernel<<<TOTAL / 64, 256, 0, stream>>>(x_seq, wx, xwb);
    dim3 ggrid(NN / 4, TT / 2);
    gather_kernel<<<ggrid, 256, 0, stream>>>(xwb, dinv, row_ptr, csr_src, csr_norm, gcn_b, hs_b);
    lstm_persist_kernel<<<NN / 80, 512, 0, stream>>>(hs_b, wp, bias, fc_w, fc_b, out);
}

// Round 6
// 234.137 us; speedup vs baseline: 7.6777x; 1.2192x over previous
//
#include <hip/hip_runtime.h>

// Problem constants (GNNRNNModel_18270790877883)
constexpr int NN = 20000;   // nodes
constexpr int NE = 320000;  // edges
constexpr int TT = 12;      // timesteps
constexpr int CIN = 128;    // in channels
constexpr int GH = 64;      // gnn hidden
constexpr int RH = 128;     // rnn hidden
constexpr int TOTAL = TT * NN;  // 240000

typedef __attribute__((ext_vector_type(8))) short short8;
typedef __attribute__((ext_vector_type(4))) float f32x4;

__device__ __forceinline__ float rcp_fast(float x) { return __builtin_amdgcn_rcpf(x); }
__device__ __forceinline__ float sigf(float x) { return rcp_fast(1.0f + __expf(-x)); }
__device__ __forceinline__ float tanh_fast(float x) { return 1.0f - 2.0f * rcp_fast(__expf(2.0f * x) + 1.0f); }

__device__ __forceinline__ unsigned short f2b_rn(float x) {
    union { float f; unsigned int u; } v; v.f = x;
    unsigned int r = v.u + 0x7FFFu + ((v.u >> 16) & 1u);
    return (unsigned short)(r >> 16);
}
__device__ __forceinline__ float b2f(unsigned short b) {
    union { unsigned int u; float f; } v; v.u = ((unsigned int)b) << 16;
    return v.f;
}
__device__ __forceinline__ float b2f_lo(unsigned int u) {
    union { unsigned int u; float f; } v; v.u = u << 16;
    return v.f;
}
__device__ __forceinline__ float b2f_hi(unsigned int u) {
    union { unsigned int u; float f; } v; v.u = u & 0xFFFF0000u;
    return v.f;
}

__device__ __forceinline__ void gload_lds16(const void* g, void* l) {
    __builtin_amdgcn_global_load_lds((const __attribute__((address_space(1))) void*)g,
                                     (__attribute__((address_space(3))) void*)l, 16, 0, 0);
}

// ---------------- graph preprocessing ----------------

__global__ __launch_bounds__(256) void degree_kernel(const int* __restrict__ dst, int* __restrict__ deg) {
    int e = blockIdx.x * blockDim.x + threadIdx.x;
    if (e < NE) atomicAdd(&deg[dst[e]], 1);
}

__global__ __launch_bounds__(256) void dinv_kernel(const int* __restrict__ deg, float* __restrict__ dinv) {
    int n = blockIdx.x * blockDim.x + threadIdx.x;
    if (n < NN) dinv[n] = rsqrtf((float)deg[n] + 1.0f);  // +1 self loop
}

__global__ __launch_bounds__(1024) void scan_kernel(const int* __restrict__ deg, int* __restrict__ row_ptr,
                                                    int* __restrict__ cursor) {
    __shared__ int sums[1024];
    int t = threadIdx.x;
    const int per = (NN + 1023) / 1024;
    int start = t * per;
    int end = min(start + per, NN);
    int s = 0;
    for (int i = start; i < end; ++i) s += deg[i];
    sums[t] = s;
    __syncthreads();
    for (int off = 1; off < 1024; off <<= 1) {
        int v = (t >= off) ? sums[t - off] : 0;
        __syncthreads();
        sums[t] += v;
        __syncthreads();
    }
    int run = (t == 0) ? 0 : sums[t - 1];
    for (int i = start; i < end; ++i) {
        row_ptr[i] = run;
        cursor[i] = run;
        run += deg[i];
    }
    if (t == 1023) row_ptr[NN] = sums[1023];
}

__global__ __launch_bounds__(256) void scatter_kernel(const int* __restrict__ src, const int* __restrict__ dst,
                                                      const float* __restrict__ dinv, int* __restrict__ cursor,
                                                      int* __restrict__ csr_src, float* __restrict__ csr_norm) {
    int e = blockIdx.x * blockDim.x + threadIdx.x;
    if (e >= NE) return;
    int d = dst[e], s = src[e];
    int pos = atomicAdd(&cursor[d], 1);
    csr_src[pos] = s;
    csr_norm[pos] = dinv[s] * dinv[d];
}

// ---------------- weight prep (bf16, XOR-swizzled granule layout) ----------------

__global__ __launch_bounds__(256) void wprep_lstm_kernel(const float* __restrict__ w_ih, const float* __restrict__ w_hh,
                                                         unsigned short* __restrict__ wp) {
    int gidx = blockIdx.x * blockDim.x + threadIdx.x;  // granule id
    if (gidx >= 6 * 512 * 4) return;
    int gs = gidx & 3;
    int col = (gidx >> 2) & 511;
    int chunk = gidx >> 11;
    int g = gs ^ ((col >> 1) & 3);
    int k0 = chunk * 32 + g * 8;
    short8 v;
#pragma unroll
    for (int j = 0; j < 8; ++j) {
        int k = k0 + j;
        float f = (k < 64) ? w_ih[col * 64 + k] : w_hh[col * 128 + (k - 64)];
        v[j] = (short)f2b_rn(f);
    }
    *reinterpret_cast<short8*>(wp + (size_t)gidx * 8) = v;
}

__global__ __launch_bounds__(256) void wprep_gcn_kernel(const float* __restrict__ gcn_w, unsigned short* __restrict__ wx) {
    int gidx = blockIdx.x * blockDim.x + threadIdx.x;
    if (gidx >= 4 * 64 * 4) return;
    int gs = gidx & 3;
    int col = (gidx >> 2) & 63;
    int chunk = gidx >> 8;
    int g = gs ^ ((col >> 1) & 3);
    int k0 = chunk * 32 + g * 8;
    short8 v;
#pragma unroll
    for (int j = 0; j < 8; ++j) v[j] = (short)f2b_rn(gcn_w[(k0 + j) * 64 + col]);
    *reinterpret_cast<short8*>(wx + (size_t)gidx * 8) = v;
}

__global__ __launch_bounds__(256) void bias_kernel(const float* __restrict__ b_ih, const float* __restrict__ b_hh,
                                                   float* __restrict__ bias) {
    int i = blockIdx.x * blockDim.x + threadIdx.x;
    if (i < 4 * RH) bias[i] = b_ih[i] + b_hh[i];
}

// ---------------- batched XW: bf16 MFMA GEMM  M=240000 K=128 N=64, bf16 out ----------------

__global__ __launch_bounds__(256) void xw_mfma_kernel(const float* __restrict__ x,          // [TOTAL,128]
                                                      const unsigned short* __restrict__ wx,
                                                      unsigned short* __restrict__ xwb) {   // [TOTAL,64] bf16
    __shared__ __align__(16) char As[4 * 4096];  // [chunk][64 rows][4 gs][16B]
    __shared__ __align__(16) char Bs[4 * 4096];  // [chunk][64 cols][4 gs][16B]
    int tid = threadIdx.x;
    int lane = tid & 63, w = tid >> 6;
    int m0 = blockIdx.x * 64;

#pragma unroll
    for (int j = 0; j < 4; ++j) {
        const unsigned short* src = wx + (size_t)(w * 4 + j) * 512 + lane * 8;
        gload_lds16(src, Bs + (w * 4 + j) * 1024);
    }
    {
        int row = tid >> 2, gs = tid & 3;
        int srow = m0 + row;
        int g = gs ^ ((row >> 1) & 3);
        const float* sp = x + (size_t)srow * CIN + g * 8;
#pragma unroll
        for (int c = 0; c < 4; ++c) {
            float4 f0 = *reinterpret_cast<const float4*>(sp + c * 32);
            float4 f1 = *reinterpret_cast<const float4*>(sp + c * 32 + 4);
            short8 v;
            v[0] = (short)f2b_rn(f0.x); v[1] = (short)f2b_rn(f0.y);
            v[2] = (short)f2b_rn(f0.z); v[3] = (short)f2b_rn(f0.w);
            v[4] = (short)f2b_rn(f1.x); v[5] = (short)f2b_rn(f1.y);
            v[6] = (short)f2b_rn(f1.z); v[7] = (short)f2b_rn(f1.w);
            *reinterpret_cast<short8*>(As + c * 4096 + row * 64 + gs * 16) = v;
        }
    }
    __syncthreads();

    f32x4 acc[4] = {};
    int rl = w * 16 + (lane & 15);
    int o = lane >> 4;
#pragma unroll
    for (int c = 0; c < 4; ++c) {
        int gsa = o ^ ((rl >> 1) & 3);
        short8 a = *reinterpret_cast<const short8*>(As + c * 4096 + rl * 64 + gsa * 16);
#pragma unroll
        for (int cn = 0; cn < 4; ++cn) {
            int col = cn * 16 + (lane & 15);
            int gsb = o ^ ((col >> 1) & 3);
            short8 b = *reinterpret_cast<const short8*>(Bs + c * 4096 + col * 64 + gsb * 16);
            acc[cn] = __builtin_amdgcn_mfma_f32_16x16x32_bf16(a, b, acc[cn], 0, 0, 0);
        }
    }
#pragma unroll
    for (int cn = 0; cn < 4; ++cn)
#pragma unroll
        for (int r = 0; r < 4; ++r) {
            int row = m0 + w * 16 + (lane >> 4) * 4 + r;
            int col = cn * 16 + (lane & 15);
            xwb[(size_t)row * GH + col] = f2b_rn(acc[cn][r]);
        }
}

// ---------------- batched GCN aggregation ----------------
// Wave = 2 nodes x 2 timesteps. lane: g = lane>>5 selects node, sl = lane&31 covers 2 channels (u32).
// One load inst gathers 256B (both nodes), 16 loads in flight per inner step.

__global__ __launch_bounds__(256) void gather_kernel(const unsigned short* __restrict__ xwb, const float* __restrict__ dinv,
                                                     const int* __restrict__ row_ptr, const int* __restrict__ csr_src,
                                                     const float* __restrict__ csr_norm, const float* __restrict__ gcn_b,
                                                     unsigned short* __restrict__ hs_b) {
    int t0 = blockIdx.y * 2;
    int wpair = (blockIdx.x * blockDim.x + threadIdx.x) >> 6;  // node-pair id (0..9999)
    int lane = threadIdx.x & 63;
    int g = lane >> 5, sl = lane & 31;
    int node = wpair * 2 + g;
    const unsigned int* sl0 = (const unsigned int*)(xwb + (size_t)t0 * NN * GH);
    const unsigned int* sl1 = sl0 + (size_t)NN * 32;

    float dv = dinv[node];
    float b0 = gcn_b[sl * 2], b1 = gcn_b[sl * 2 + 1];
    unsigned int u0 = sl0[(size_t)node * 32 + sl];
    unsigned int u1 = sl1[(size_t)node * 32 + sl];
    float a0x = b0 + dv * dv * b2f_lo(u0);
    float a0y = b1 + dv * dv * b2f_hi(u0);
    float a1x = b0 + dv * dv * b2f_lo(u1);
    float a1y = b1 + dv * dv * b2f_hi(u1);

    int e0 = row_ptr[node];
    int deg = row_ptr[node + 1] - e0;
    // wave-max batches (deg is group-uniform; grab other group's via lane 0 / 32)
    int degA = __shfl(deg, 0), degB = __shfl(deg, 32);
    int dmax = max(degA, degB);

    for (int base = 0; base < dmax; base += 32) {
        int cnt = min(deg - base, 32);           // may be <= 0 for one group
        bool valid = sl < cnt;
        int myidx = valid ? csr_src[e0 + base + sl] : 0;
        float mynm = valid ? csr_norm[e0 + base + sl] : 0.f;
        int c8 = (max(cnt, 0) + 7) & ~7;
        int c8o = __shfl(c8, (1 - g) << 5);      // other group's c8
        int c8w = max(c8, c8o);
        for (int j = 0; j < c8w; j += 8) {
            int s0 = __shfl(myidx, (g << 5) + j + 0), s1 = __shfl(myidx, (g << 5) + j + 1);
            int s2 = __shfl(myidx, (g << 5) + j + 2), s3 = __shfl(myidx, (g << 5) + j + 3);
            int s4 = __shfl(myidx, (g << 5) + j + 4), s5 = __shfl(myidx, (g << 5) + j + 5);
            int s6 = __shfl(myidx, (g << 5) + j + 6), s7 = __shfl(myidx, (g << 5) + j + 7);
            float n0 = __shfl(mynm, (g << 5) + j + 0), n1 = __shfl(mynm, (g << 5) + j + 1);
            float n2 = __shfl(mynm, (g << 5) + j + 2), n3 = __shfl(mynm, (g << 5) + j + 3);
            float n4 = __shfl(mynm, (g << 5) + j + 4), n5 = __shfl(mynm, (g << 5) + j + 5);
            float n6 = __shfl(mynm, (g << 5) + j + 6), n7 = __shfl(mynm, (g << 5) + j + 7);
            unsigned int p0 = sl0[(size_t)s0 * 32 + sl], q0 = sl1[(size_t)s0 * 32 + sl];
            unsigned int p1 = sl0[(size_t)s1 * 32 + sl], q1 = sl1[(size_t)s1 * 32 + sl];
            unsigned int p2 = sl0[(size_t)s2 * 32 + sl], q2 = sl1[(size_t)s2 * 32 + sl];
            unsigned int p3 = sl0[(size_t)s3 * 32 + sl], q3 = sl1[(size_t)s3 * 32 + sl];
            unsigned int p4 = sl0[(size_t)s4 * 32 + sl], q4 = sl1[(size_t)s4 * 32 + sl];
            unsigned int p5 = sl0[(size_t)s5 * 32 + sl], q5 = sl1[(size_t)s5 * 32 + sl];
            unsigned int p6 = sl0[(size_t)s6 * 32 + sl], q6 = sl1[(size_t)s6 * 32 + sl];
            unsigned int p7 = sl0[(size_t)s7 * 32 + sl], q7 = sl1[(size_t)s7 * 32 + sl];
            a0x += n0 * b2f_lo(p0); a0y += n0 * b2f_hi(p0); a1x += n0 * b2f_lo(q0); a1y += n0 * b2f_hi(q0);
            a0x += n1 * b2f_lo(p1); a0y += n1 * b2f_hi(p1); a1x += n1 * b2f_lo(q1); a1y += n1 * b2f_hi(q1);
            a0x += n2 * b2f_lo(p2); a0y += n2 * b2f_hi(p2); a1x += n2 * b2f_lo(q2); a1y += n2 * b2f_hi(q2);
            a0x += n3 * b2f_lo(p3); a0y += n3 * b2f_hi(p3); a1x += n3 * b2f_lo(q3); a1y += n3 * b2f_hi(q3);
            a0x += n4 * b2f_lo(p4); a0y += n4 * b2f_hi(p4); a1x += n4 * b2f_lo(q4); a1y += n4 * b2f_hi(q4);
            a0x += n5 * b2f_lo(p5); a0y += n5 * b2f_hi(p5); a1x += n5 * b2f_lo(q5); a1y += n5 * b2f_hi(q5);
            a0x += n6 * b2f_lo(p6); a0y += n6 * b2f_hi(p6); a1x += n6 * b2f_lo(q6); a1y += n6 * b2f_hi(q6);
            a0x += n7 * b2f_lo(p7); a0y += n7 * b2f_hi(p7); a1x += n7 * b2f_lo(q7); a1y += n7 * b2f_hi(q7);
        }
    }
    unsigned int o0 = (unsigned int)f2b_rn(a0x) | ((unsigned int)f2b_rn(a0y) << 16);
    unsigned int o1 = (unsigned int)f2b_rn(a1x) | ((unsigned int)f2b_rn(a1y) << 16);
    ((unsigned int*)hs_b)[((size_t)t0 * NN + node) * 32 + sl] = o0;
    ((unsigned int*)hs_b)[((size_t)(t0 + 1) * NN + node) * 32 + sl] = o1;
}

// ---------------- persistent LSTM ----------------

#define HS_OFF 0            // 2 slots x [2 chunks][80 rows][4 gs][16B] = 2 x 10240
#define HA_OFF 20480        // [4 chunks][80 rows][4 gs][16B] = 20480
#define RED_OFF 40960       // float [8][80] = 2560
#define SMEM_BYTES 43520

__global__ __launch_bounds__(512, 2) void lstm_persist_kernel(const unsigned short* __restrict__ hs_all, // [TT,NN,64]
                                                              const unsigned short* __restrict__ wp,     // [6][512][4][8]
                                                              const float* __restrict__ bias,            // [512]
                                                              const float* __restrict__ fc_w,            // [128]
                                                              const float* __restrict__ fc_b,            // [1]
                                                              float* __restrict__ out) {                 // [NN]
    __shared__ __align__(16) char smem[SMEM_BYTES];
    int tid = threadIdx.x;
    int lane = tid & 63, w = tid >> 6;
    int l15 = lane & 15, o = lane >> 4;
    int base = blockIdx.x * 80;

    int sw = o ^ ((l15 >> 1) & 3);       // shared swizzle for all A reads (and B prep layout)
    int colbase = w * 16 + l15;          // this thread's rh-col
    float bi = bias[colbase], bff = bias[128 + colbase], bg = bias[256 + colbase], bo = bias[384 + colbase];
    float fcw = fc_w[colbase];

    // h-write constants: k = 64 + colbase -> chunk, granule, elem
    int h_chunk = w >> 1;                          // 0..3
    int h_g = ((w & 1) << 1) + (l15 >> 3);         // granule within 32-k chunk
    int h_j = l15 & 7;                             // elem within granule

    // hoist ALL B fragments into registers (96 VGPRs) and PIN them with opaque asm so the
    // compiler cannot rematerialize the loads inside the t-loop.
    short8 breg[6][4];
#pragma unroll
    for (int c = 0; c < 6; ++c)
#pragma unroll
        for (int g = 0; g < 4; ++g) {
            size_t goff = ((size_t)(c * 512 + g * 128 + colbase) * 4 + sw) * 8;
            breg[c][g] = *reinterpret_cast<const short8*>(wp + goff);
            asm volatile("" : "+v"(breg[c][g]));
        }

    // prologue: zero h region, stage hs[0] into slot 0
    {
#pragma unroll
        for (int i = 0; i < 10; ++i) ((int*)(smem + HA_OFF))[tid + i * 512] = 0;
#pragma unroll
        for (int j = 0; j < 2; ++j) {
            int gi = j * 512 + tid;
            if (gi < 640) {
                int cc = (gi >= 320) ? 1 : 0;
                int rem = gi - cc * 320;
                int row = rem >> 2, gs = rem & 3;
                int g = gs ^ ((row >> 1) & 3);
                const unsigned short* src = hs_all + ((size_t)(base + row)) * 64 + cc * 32 + g * 8;
                gload_lds16(src, smem + HS_OFF + gi * 16);
            }
        }
    }

    float c_reg[5][4] = {};
    f32x4 acc[5][4];

#pragma unroll 1
    for (int t = 0; t < TT; ++t) {
        __syncthreads();  // drains vmcnt: hs[t] staged + prev h-writes visible

        // prefetch hs[t+1] into other slot
        if (t + 1 < TT) {
            char* dstb = smem + HS_OFF + ((t + 1) & 1) * 10240;
#pragma unroll
            for (int j = 0; j < 2; ++j) {
                int gi = j * 512 + tid;
                if (gi < 640) {
                    int cc = (gi >= 320) ? 1 : 0;
                    int rem = gi - cc * 320;
                    int row = rem >> 2, gs = rem & 3;
                    int g = gs ^ ((row >> 1) & 3);
                    const unsigned short* src = hs_all + ((size_t)(t + 1) * NN + base + row) * 64 + cc * 32 + g * 8;
                    gload_lds16(src, dstb + gi * 16);
                }
            }
        }

#pragma unroll
        for (int mi = 0; mi < 5; ++mi)
#pragma unroll
            for (int g = 0; g < 4; ++g) acc[mi][g] = (f32x4){0.f, 0.f, 0.f, 0.f};

        const char* hsb = smem + HS_OFF + (t & 1) * 10240;
#pragma unroll
        for (int c = 0; c < 6; ++c) {
            const char* abase = (c < 2) ? (hsb + c * 5120) : (smem + HA_OFF + (c - 2) * 5120);
            short8 a[5];
#pragma unroll
            for (int mi = 0; mi < 5; ++mi)
                a[mi] = *reinterpret_cast<const short8*>(abase + (mi * 16 + l15) * 64 + sw * 16);
#pragma unroll
            for (int g = 0; g < 4; ++g)
#pragma unroll
                for (int mi = 0; mi < 5; ++mi)
                    acc[mi][g] = __builtin_amdgcn_mfma_f32_16x16x32_bf16(a[mi], breg[c][g], acc[mi][g], 0, 0, 0);
        }

        __syncthreads();  // all reads of h region done before overwrite

        // epilogue: thread covers rows mi*16 + o*4 + r, col = colbase
        if (t + 1 < TT) {
#pragma unroll
            for (int mi = 0; mi < 5; ++mi)
#pragma unroll
                for (int r = 0; r < 4; ++r) {
                    float iv = sigf(acc[mi][0][r] + bi);
                    float fv = sigf(acc[mi][1][r] + bff);
                    float gv = tanh_fast(acc[mi][2][r] + bg);
                    float ov = sigf(acc[mi][3][r] + bo);
                    float cnew = fv * c_reg[mi][r] + iv * gv;
                    c_reg[mi][r] = cnew;
                    float hv = ov * tanh_fast(cnew);
                    int row = mi * 16 + o * 4 + r;
                    int gs_h = h_g ^ ((row >> 1) & 3);
                    *(unsigned short*)(smem + HA_OFF + h_chunk * 5120 + row * 64 + gs_h * 16 + h_j * 2) = f2b_rn(hv);
                }
        } else {
            // final step: fuse FC.  partial = h * fc_w[col]; reduce over 16 cols via shfl, stash per wave.
#pragma unroll
            for (int mi = 0; mi < 5; ++mi)
#pragma unroll
                for (int r = 0; r < 4; ++r) {
                    float iv = sigf(acc[mi][0][r] + bi);
                    float fv = sigf(acc[mi][1][r] + bff);
                    float gv = tanh_fast(acc[mi][2][r] + bg);
                    float ov = sigf(acc[mi][3][r] + bo);
                    float cnew = fv * c_reg[mi][r] + iv * gv;
                    float hv = ov * tanh_fast(cnew);
                    float p = hv * fcw;
                    p += __shfl_xor(p, 1);
                    p += __shfl_xor(p, 2);
                    p += __shfl_xor(p, 4);
                    p += __shfl_xor(p, 8);
                    if (l15 == 0) {
                        int row = mi * 16 + o * 4 + r;
                        ((float*)(smem + RED_OFF))[w * 80 + row] = p;
                    }
                }
        }
    }
    __syncthreads();
    if (tid < 80) {
        const float* red = (const float*)(smem + RED_OFF);
        float s = 0.f;
#pragma unroll
        for (int w8 = 0; w8 < 8; ++w8) s += red[w8 * 80 + tid];
        out[base + tid] = s + fc_b[0];
    }
}

// ---------------- host ----------------

extern "C" void kernel_launch(void* const* d_in, const int* in_sizes, int n_in,
                              void* d_out, int out_size, void* d_ws, size_t ws_size,
                              hipStream_t stream) {
    const float* x_seq = (const float*)d_in[0];
    const int* edge = (const int*)d_in[1];
    const float* gcn_w = (const float*)d_in[2];
    const float* gcn_b = (const float*)d_in[3];
    const float* w_ih = (const float*)d_in[4];
    const float* w_hh = (const float*)d_in[5];
    const float* b_ih = (const float*)d_in[6];
    const float* b_hh = (const float*)d_in[7];
    const float* fc_w = (const float*)d_in[8];
    const float* fc_b = (const float*)d_in[9];
    float* out = (float*)d_out;

    char* w = (char*)d_ws;
    auto carve = [&](size_t bytes) {
        void* p = (void*)w;
        w += (bytes + 255) & ~(size_t)255;
        return p;
    };
    float* dinv = (float*)carve(NN * 4);
    int* deg = (int*)carve(NN * 4);
    int* row_ptr = (int*)carve((NN + 1) * 4);
    int* cursor = (int*)carve(NN * 4);
    int* csr_src = (int*)carve(NE * 4);
    float* csr_norm = (float*)carve(NE * 4);
    unsigned short* xwb = (unsigned short*)carve((size_t)TOTAL * GH * 2);
    unsigned short* hs_b = (unsigned short*)carve((size_t)TOTAL * GH * 2);
    unsigned short* wp = (unsigned short*)carve((size_t)6 * 512 * 4 * 8 * 2);
    unsigned short* wx = (unsigned short*)carve((size_t)4 * 64 * 4 * 8 * 2);
    float* bias = (float*)carve(512 * 4);

    hipMemsetAsync(deg, 0, NN * 4, stream);

    const int* e_src = edge;
    const int* e_dst = edge + NE;

    degree_kernel<<<(NE + 255) / 256, 256, 0, stream>>>(e_dst, deg);
    dinv_kernel<<<(NN + 255) / 256, 256, 0, stream>>>(deg, dinv);
    scan_kernel<<<1, 1024, 0, stream>>>(deg, row_ptr, cursor);
    scatter_kernel<<<(NE + 255) / 256, 256, 0, stream>>>(e_src, e_dst, dinv, cursor, csr_src, csr_norm);

    wprep_lstm_kernel<<<(6 * 512 * 4 + 255) / 256, 256, 0, stream>>>(w_ih, w_hh, wp);
    wprep_gcn_kernel<<<(4 * 64 * 4 + 255) / 256, 256, 0, stream>>>(gcn_w, wx);
    bias_kernel<<<2, 256, 0, stream>>>(b_ih, b_hh, bias);

    xw_mfma_kernel<<<TOTAL / 64, 256, 0, stream>>>(x_seq, wx, xwb);
    dim3 ggrid(NN / 2 / 4, TT / 2);
    gather_kernel<<<ggrid, 256, 0, stream>>>(xwb, dinv, row_ptr, csr_src, csr_norm, gcn_b, hs_b);
    lstm_persist_kernel<<<NN / 80, 512, 0, stream>>>(hs_b, wp, bias, fc_w, fc_b, out);
}